// Round 7
// baseline (1114.798 us; speedup 1.0000x reference)
//
#include <hip/hip_runtime.h>
#include <hip/hip_bf16.h>

// Problem constants: B=32, C=3, H=W=128, D=512, K=512, S=4, HL=32, NPOS=32768
#define NPOS 32768
#define CHUNK 8192

// OUTPUT = FP32 (reference dtype). d_out fp32 element layout:
//   out_r [0, 1572864) | out_z [1572864, 18350080) | out_e [18350080, 35127296)
// Scratch inside the out_e fp32 region (67,108,864 B):
//   head: zbuf CHUNK*512 fp32 = 16,777,216 B | partS 131,072 B | partI 131,072 B
//   tail (last 262,144 B = b=31, d in [448,512)):
//     idx 131,072 | U 98,304 | w2 2,048 | flag 64
// k_emb skips (b==31 && d>=448); k_fixup (1 block) writes those last after
// staging idx/flag in LDS. d_ws is never touched.

static __device__ __forceinline__ float bfu(unsigned short h) {
    return __uint_as_float(((unsigned int)h) << 16);
}
// branchy input read: flag=1 -> bf16, flag=0 -> fp32 (scalar only: d_in
// pointers assumed no better than 2B-aligned)
static __device__ __forceinline__ float ldin(const void* p, size_t i, int flag) {
    return flag ? bfu(((const unsigned short*)p)[i]) : ((const float*)p)[i];
}

// ---------------------------------------------------------------------------
// S0: input dtype sniffer on the codebook (N(0,1), 512x512). bf16-read column
// sums of squares ~512; fp32 data misread as bf16 -> wild exponents -> out of
// [100,2000] almost surely. flag=1 means inputs are bf16.
// ---------------------------------------------------------------------------
__global__ void k_sniff(const void* __restrict__ cb, int* __restrict__ flag) {
    __shared__ float s[64];
    const int k = threadIdx.x;
    const unsigned short* u = (const unsigned short*)cb;
    float acc = 0.f;
    for (int d = 0; d < 512; ++d) {
        float v = bfu(u[d * 512 + k]);
        acc = fmaf(v, v, acc);
    }
    s[k] = acc;
    __syncthreads();
    if (k == 0) {
        int ok = 1;
        for (int i = 0; i < 64; ++i) {
            float a = s[i];
            if (!(a >= 100.f && a <= 2000.f)) ok = 0;   // NaN/inf also fail
        }
        *flag = ok;
    }
}

// ---------------------------------------------------------------------------
// w2[k] = sum_d cb[d][k]^2 in double (score bias ~1e-13, below np noise).
// ---------------------------------------------------------------------------
__global__ void k_w2(const void* __restrict__ cb, const int* __restrict__ flagp,
                     float* __restrict__ w2) {
    const int flag = *flagp;
    int k = blockIdx.x * 64 + threadIdx.x;
    double acc = 0.0;
    for (int d = 0; d < 512; ++d) {
        double v = (double)ldin(cb, (size_t)d * 512 + k, flag);
        acc += v * v;
    }
    w2[k] = (float)acc;
}

// ---------------------------------------------------------------------------
// U[k][c*16+u*4+v] = sum_d cb[d][k]*Wd[c][d][3-u][3-v] + bd[c]
// (jax conv_transpose, stride==kernel, transpose_kernel=False: output pixel
//  4i+u couples to latent i via tap (3-u,3-v))
// ---------------------------------------------------------------------------
__global__ __launch_bounds__(256) void k_udec(
        const void* __restrict__ cb, const void* __restrict__ Wd,
        const void* __restrict__ bd, const int* __restrict__ flagp,
        float* __restrict__ U) {
    const int flag = *flagp;
    const int t = threadIdx.x;
    const int k = blockIdx.x * 16 + (t >> 4);
    const int j = t & 15;
    const int u = (j >> 2) & 3, v = j & 3;
    int woff[3];
    #pragma unroll
    for (int m = 0; m < 3; ++m)
        woff[m] = m * 8192 + (3 - u) * 4 + (3 - v);   // Wd flat = c*8192 + d*16 + r*4 + s
    float a0 = 0.f, a1 = 0.f, a2 = 0.f;
    for (int d = 0; d < 512; ++d) {
        float cw = ldin(cb, (size_t)d * 512 + k, flag);
        a0 = fmaf(cw, ldin(Wd, woff[0] + d * 16, flag), a0);
        a1 = fmaf(cw, ldin(Wd, woff[1] + d * 16, flag), a1);
        a2 = fmaf(cw, ldin(Wd, woff[2] + d * 16, flag), a2);
    }
    U[k * 48 +  0 + j] = a0 + ldin(bd, 0, flag);
    U[k * 48 + 16 + j] = a1 + ldin(bd, 1, flag);
    U[k * 48 + 32 + j] = a2 + ldin(bd, 2, flag);
}

// ---------------------------------------------------------------------------
// Encoder: stride-4 4x4 VALID conv + bias + ReLU for positions
// [P0base, P0base+CHUNK). z fp32 pos-major [local_pos][512] in zbuf.
// ---------------------------------------------------------------------------
__global__ __launch_bounds__(512) void k_encode(
        const void* __restrict__ x, const void* __restrict__ We,
        const void* __restrict__ be, const int* __restrict__ flagp,
        float* __restrict__ zbuf, int P0base) {
    __shared__ float patch[64][48];
    const int flag = *flagp;
    const int t = threadIdx.x;
    const int P0loc = blockIdx.x * 64;

    for (int e = t; e < 3072; e += 512) {
        int pid = e / 48, kk = e % 48;
        int c = kk >> 4, r = (kk >> 2) & 3, s = kk & 3;
        int pos = P0base + P0loc + pid;
        int b = pos >> 10, sp = pos & 1023, i = sp >> 5, j = sp & 31;
        int ga = ((b * 3 + c) * 128 + (i * 4 + r)) * 128 + (j * 4 + s);
        patch[pid][kk] = ldin(x, ga, flag);
    }
    const int d = t;
    float w[48];
    #pragma unroll
    for (int i = 0; i < 48; ++i) w[i] = ldin(We, d * 48 + i, flag);
    const float bias = ldin(be, d, flag);
    __syncthreads();

    for (int p = 0; p < 64; ++p) {
        const float4* pr = reinterpret_cast<const float4*>(patch[p]);
        float acc = bias;
        #pragma unroll
        for (int q4 = 0; q4 < 12; ++q4) {
            float4 v = pr[q4];
            acc = fmaf(v.x, w[4*q4+0], acc);
            acc = fmaf(v.y, w[4*q4+1], acc);
            acc = fmaf(v.z, w[4*q4+2], acc);
            acc = fmaf(v.w, w[4*q4+3], acc);
        }
        zbuf[(size_t)(P0loc + p) * 512 + d] = fmaxf(acc, 0.f);
    }
}

// ---------------------------------------------------------------------------
// Distance partial argmin: fp32 VALU GEMM, tile 64 pos x 128 k, d-chunks of
// 64. score = w2[k] - 2*(z.w_k) (z2 per-pos constant dropped).
// ---------------------------------------------------------------------------
__global__ __launch_bounds__(256) void k_dist(
        const float* __restrict__ zbuf, const void* __restrict__ cb,
        const int* __restrict__ flagp, const float* __restrict__ w2,
        float* __restrict__ partS, int* __restrict__ partI) {
    __shared__ float zl[64][68];
    __shared__ float cbl[64][132];
    __shared__ float redS[64][17];
    __shared__ int   redI[64][17];

    const int flag = *flagp;
    const int t  = threadIdx.x;
    const int tx = t & 15;
    const int ty = t >> 4;
    const int P0 = blockIdx.x * 64;
    const int K0 = blockIdx.y * 128;

    float accs[4][8];
    #pragma unroll
    for (int i = 0; i < 4; ++i)
        #pragma unroll
        for (int j = 0; j < 8; ++j) accs[i][j] = 0.f;

    for (int dc = 0; dc < 512; dc += 64) {
        #pragma unroll
        for (int it = 0; it < 4; ++it) {
            int pi = (t & 15) + 16 * it;
            int dr = (t >> 4) * 4;
            float4 g = *reinterpret_cast<const float4*>(
                &zbuf[(size_t)(P0 + pi) * 512 + dc + dr]);
            zl[dr + 0][pi] = g.x; zl[dr + 1][pi] = g.y;
            zl[dr + 2][pi] = g.z; zl[dr + 3][pi] = g.w;
        }
        // scalar staging of cb tile (input alignment/dtype safe)
        for (int e = t; e < 8192; e += 256) {
            int row = e >> 7, col = e & 127;
            cbl[row][col] = ldin(cb, (size_t)(dc + row) * 512 + K0 + col, flag);
        }
        __syncthreads();

        #pragma unroll 4
        for (int dd = 0; dd < 64; ++dd) {
            float4 zv = *reinterpret_cast<const float4*>(&zl[dd][ty * 4]);
            float4 b0 = *reinterpret_cast<const float4*>(&cbl[dd][tx * 4]);
            float4 b1 = *reinterpret_cast<const float4*>(&cbl[dd][64 + tx * 4]);
            float zr[4] = {zv.x, zv.y, zv.z, zv.w};
            float br[8] = {b0.x, b0.y, b0.z, b0.w, b1.x, b1.y, b1.z, b1.w};
            #pragma unroll
            for (int i = 0; i < 4; ++i)
                #pragma unroll
                for (int j = 0; j < 8; ++j)
                    accs[i][j] = fmaf(zr[i], br[j], accs[i][j]);
        }
        __syncthreads();
    }

    float w2g[8];
    #pragma unroll
    for (int j = 0; j < 8; ++j)
        w2g[j] = w2[K0 + tx * 4 + (j & 3) + (j >> 2) * 64];

    #pragma unroll
    for (int i = 0; i < 4; ++i) {
        float bs = 1e30f; int bk = 511;
        #pragma unroll
        for (int j = 0; j < 8; ++j) {
            int k = K0 + tx * 4 + (j & 3) + (j >> 2) * 64;
            float s = w2g[j] - 2.f * accs[i][j];
            if (s < bs || (s == bs && k < bk)) { bs = s; bk = k; }
        }
        redS[ty * 4 + i][tx] = bs;
        redI[ty * 4 + i][tx] = bk;
    }
    __syncthreads();

    if (t < 64) {
        float bs = redS[t][0]; int bk = redI[t][0];
        for (int q = 1; q < 16; ++q) {
            float s = redS[t][q]; int k = redI[t][q];
            if (s < bs || (s == bs && k < bk)) { bs = s; bk = k; }
        }
        partS[blockIdx.y * CHUNK + P0 + t] = bs;
        partI[blockIdx.y * CHUNK + P0 + t] = bk;
    }
}

// ---------------------------------------------------------------------------
__global__ void k_combine(const float* __restrict__ partS,
                          const int* __restrict__ partI, int* __restrict__ idx,
                          int P0base) {
    int p = blockIdx.x * 256 + threadIdx.x;
    float bs = partS[p]; int bk = partI[p];
    #pragma unroll
    for (int kt = 1; kt < 4; ++kt) {
        float s = partS[kt * CHUNK + p];
        int   k = partI[kt * CHUNK + p];
        if (s < bs || (s == bs && k < bk)) { bs = s; bk = k; }
    }
    idx[P0base + p] = bk & 511;
}

// ---------------------------------------------------------------------------
// z_e output for one chunk: fp32, (B,512,32,32) d-major, LDS transpose.
// ---------------------------------------------------------------------------
__global__ __launch_bounds__(256) void k_outz(
        const float* __restrict__ zbuf, float* __restrict__ out_z, int P0base) {
    __shared__ float tz[64][65];
    const int t = threadIdx.x;
    const int P0loc = blockIdx.x * 64;
    const int P0g = P0base + P0loc;
    const int D0 = blockIdx.y * 64;

    for (int it = 0; it < 16; ++it) {
        int pi = (t >> 6) + 4 * it;
        int dl = t & 63;
        tz[dl][pi] = zbuf[(size_t)(P0loc + pi) * 512 + D0 + dl];
    }
    __syncthreads();
    const int b = P0g >> 10, SP0 = P0g & 1023;
    for (int it = 0; it < 16; ++it) {
        int row = (t >> 6) + 4 * it;
        int pl = t & 63;
        out_z[((size_t)(b * 512 + D0 + row)) * 1024 + SP0 + pl] = tz[row][pl];
    }
}

// ---------------------------------------------------------------------------
// recon = sigmoid(U[idx[pos]]) scattered into (B,3,128,128), fp32.
// ---------------------------------------------------------------------------
__global__ __launch_bounds__(256) void k_recon(
        const float* __restrict__ U, const int* __restrict__ idx,
        float* __restrict__ out_r) {
    const int pos = blockIdx.x * 256 + threadIdx.x;
    const int id = idx[pos] & 511;
    const int b = pos >> 10, sp = pos & 1023, i = sp >> 5, j = sp & 31;
    const float* u = &U[(size_t)id * 48];
    #pragma unroll
    for (int c = 0; c < 3; ++c) {
        #pragma unroll
        for (int uu = 0; uu < 4; ++uu) {
            float4 q = *reinterpret_cast<const float4*>(&u[c * 16 + uu * 4]);
            float4 o;
            o.x = 1.f / (1.f + __expf(-q.x));
            o.y = 1.f / (1.f + __expf(-q.y));
            o.z = 1.f / (1.f + __expf(-q.z));
            o.w = 1.f / (1.f + __expf(-q.w));
            size_t a = ((size_t)((b * 3 + c) * 128) + (i * 4 + uu)) * 128 + j * 4;
            *reinterpret_cast<float4*>(&out_r[a]) = o;
        }
    }
}

// ---------------------------------------------------------------------------
// emb = cb[:, idx] fp32 in (B,512,32,32) — all of out_e EXCEPT the scratch
// tail (b==31 && d>=448). grid = (32 b, 4 sp-tiles), block 256.
// ---------------------------------------------------------------------------
__global__ __launch_bounds__(256) void k_emb(
        const void* __restrict__ cb, const int* __restrict__ flagp,
        const int* __restrict__ idx, float* __restrict__ out_e) {
    __shared__ int ii[256];
    const int flag = *flagp;
    const int t = threadIdx.x;
    const int b = blockIdx.x;
    const int SP0 = blockIdx.y * 256;
    ii[t] = idx[b * 1024 + SP0 + t] & 511;
    __syncthreads();
    for (int d = 0; d < 512; ++d) {
        if (b == 31 && d >= 448) break;
        out_e[((size_t)(b * 512 + d)) * 1024 + SP0 + t] =
            ldin(cb, (size_t)d * 512 + ii[t], flag);
    }
}

// ---------------------------------------------------------------------------
// Fixup: emb for the scratch-tail (b=31, d in [448,512)). Single block;
// stages idx+flag in LDS BEFORE writing (writes clobber that storage).
// ---------------------------------------------------------------------------
__global__ __launch_bounds__(256) void k_fixup(
        const void* __restrict__ cb, const int* __restrict__ flagp,
        const int* __restrict__ idx, float* __restrict__ out_e) {
    __shared__ int ii[1024];
    __shared__ int sflag;
    const int t = threadIdx.x;
    if (t == 0) sflag = *flagp;
    for (int e = t; e < 1024; e += 256) ii[e] = idx[31744 + e] & 511;
    __syncthreads();
    const int flag = sflag;
    for (int e = t; e < 65536; e += 256) {
        int d = 448 + (e >> 10), sp = e & 1023;
        out_e[((size_t)(31 * 512 + d)) * 1024 + sp] =
            ldin(cb, (size_t)d * 512 + ii[sp], flag);
    }
}

// ---------------------------------------------------------------------------
extern "C" void kernel_launch(void* const* d_in, const int* in_sizes, int n_in,
                              void* d_out, int out_size, void* d_ws, size_t ws_size,
                              hipStream_t stream) {
    const void* x  = d_in[0];
    const void* We = d_in[1];
    const void* be = d_in[2];
    const void* Wd = d_in[3];
    const void* bd = d_in[4];
    const void* cb = d_in[5];

    float* out   = (float*)d_out;
    float* out_r = out;                       // 1,572,864 fp32
    float* out_z = out + 1572864;             // 16,777,216 fp32
    float* out_e = out + 18350080;            // 16,777,216 fp32

    // Scratch inside the out_e fp32 region (67,108,864 bytes). d_ws unused.
    char* Ebase = (char*)out_e;
    float* zbuf  = (float*)(Ebase);                       // 16,777,216 B
    float* partS = (float*)(Ebase + 16777216);            //    131,072 B
    int*   partI = (int*)  (Ebase + 16908288);            //    131,072 B
    char*  Tbase = Ebase + 66846720;                      // last 262,144 B
    int*   idx   = (int*)  (Tbase);                       //    131,072 B
    float* U     = (float*)(Tbase + 131072);              //     98,304 B
    float* w2    = (float*)(Tbase + 229376);              //      2,048 B
    int*   flag  = (int*)  (Tbase + 231424);              //         64 B

    k_sniff<<<1, 64, 0, stream>>>(cb, flag);
    k_w2<<<8, 64, 0, stream>>>(cb, flag, w2);
    k_udec<<<32, 256, 0, stream>>>(cb, Wd, bd, flag, U);

    for (int c0 = 0; c0 < NPOS; c0 += CHUNK) {
        k_encode<<<CHUNK / 64, 512, 0, stream>>>(x, We, be, flag, zbuf, c0);
        k_dist<<<dim3(CHUNK / 64, 4), 256, 0, stream>>>(zbuf, cb, flag, w2, partS, partI);
        k_combine<<<CHUNK / 256, 256, 0, stream>>>(partS, partI, idx, c0);
        k_outz<<<dim3(CHUNK / 64, 8), 256, 0, stream>>>(zbuf, out_z, c0);
    }

    k_recon<<<128, 256, 0, stream>>>(U, idx, out_r);
    k_emb<<<dim3(32, 4), 256, 0, stream>>>(cb, flag, idx, out_e);
    k_fixup<<<1, 256, 0, stream>>>(cb, flag, idx, out_e);
}

// Round 8
// 649.900 us; speedup vs baseline: 1.7153x; 1.7153x over previous
//
#include <hip/hip_runtime.h>
#include <hip/hip_bf16.h>

// Problem constants: B=32, C=3, H=W=128, D=512, K=512, S=4, HL=32, NPOS=32768
#define NPOS 32768
#define CHUNK 8192

// OUTPUT = FP32. d_out fp32 element layout:
//   out_r [0, 1572864) | out_z [1572864, 18350080) | out_e [18350080, 35127296)
// Scratch in out_e region (67,108,864 B):
//   zbuf 16,777,216 | partS 131,072 | partI 131,072 | cbF 1,048,576 |
//   cWe 98,304 | cbe 2,048 | cWd 98,304 | cbd 64 | ... |
//   tail (last 262,144 B = b=31, d in [448,512)): idx 131,072 | U 98,304 | w2 2,048 | flag 64
// cbT (1 MB) lives at the start of out_r (k_emb reads it; k_recon overwrites after).
// Order: sniff -> canonW -> prepcb -> w2 -> udec -> 4x[encode,dist,combine,outz]
//        -> k_emb -> k_recon -> k_fixup.  d_ws never touched.

static __device__ __forceinline__ float bfu(unsigned short h) {
    return __uint_as_float(((unsigned int)h) << 16);
}
// branchy input read: flag=1 -> bf16, flag=0 -> fp32 (scalar; d_in may be 2B-aligned)
static __device__ __forceinline__ float ldin(const void* p, size_t i, int flag) {
    return flag ? bfu(((const unsigned short*)p)[i]) : ((const float*)p)[i];
}

// ---------------------------------------------------------------------------
// S0: input dtype sniffer on the codebook (N(0,1), 512x512).
// ---------------------------------------------------------------------------
__global__ void k_sniff(const void* __restrict__ cb, int* __restrict__ flag) {
    __shared__ float s[64];
    const int k = threadIdx.x;
    const unsigned short* u = (const unsigned short*)cb;
    float acc = 0.f;
    for (int d = 0; d < 512; ++d) {
        float v = bfu(u[d * 512 + k]);
        acc = fmaf(v, v, acc);
    }
    s[k] = acc;
    __syncthreads();
    if (k == 0) {
        int ok = 1;
        for (int i = 0; i < 64; ++i) {
            float a = s[i];
            if (!(a >= 100.f && a <= 2000.f)) ok = 0;
        }
        *flag = ok;
    }
}

// ---------------------------------------------------------------------------
// Canonicalize encoder/decoder weights to fp32 scratch (flat 49,667 elems).
// ---------------------------------------------------------------------------
__global__ void k_canonW(const void* __restrict__ We, const void* __restrict__ be,
                         const void* __restrict__ Wd, const void* __restrict__ bd,
                         const int* __restrict__ flagp, float* __restrict__ cWe,
                         float* __restrict__ cbe, float* __restrict__ cWd,
                         float* __restrict__ cbd) {
    int e = blockIdx.x * 256 + threadIdx.x;
    const int flag = *flagp;
    if (e < 24576)       cWe[e]         = ldin(We, e, flag);
    else if (e < 25088)  cbe[e - 24576] = ldin(be, e - 24576, flag);
    else if (e < 49664)  cWd[e - 25088] = ldin(Wd, e - 25088, flag);
    else if (e < 49667)  cbd[e - 49664] = ldin(bd, e - 49664, flag);
}

// ---------------------------------------------------------------------------
// Canonicalize codebook: cbF = fp32 [d][k]; cbT = fp32 [k][d] via LDS transpose.
// grid (8,8) 64x64 tiles, block 256.
// ---------------------------------------------------------------------------
__global__ __launch_bounds__(256) void k_prepcb(
        const void* __restrict__ cb, const int* __restrict__ flagp,
        float* __restrict__ cbF, float* __restrict__ cbT) {
    __shared__ float tile[64][65];
    const int flag = *flagp;
    const int D0 = blockIdx.x * 64, K0 = blockIdx.y * 64;
    const int t = threadIdx.x;
    for (int it = 0; it < 16; ++it) {
        int r = (t >> 6) + 4 * it;   // d offset
        int c = t & 63;              // k offset
        float v = ldin(cb, (size_t)(D0 + r) * 512 + K0 + c, flag);
        cbF[(size_t)(D0 + r) * 512 + K0 + c] = v;
        tile[r][c] = v;
    }
    __syncthreads();
    for (int it = 0; it < 16; ++it) {
        int r = (t >> 6) + 4 * it;   // k offset
        int c = t & 63;              // d offset
        cbT[(size_t)(K0 + r) * 512 + D0 + c] = tile[c][r];
    }
}

// ---------------------------------------------------------------------------
// w2[k] = sum_d cbF[d][k]^2 in double.
// ---------------------------------------------------------------------------
__global__ void k_w2(const float* __restrict__ cbF, float* __restrict__ w2) {
    int k = blockIdx.x * 64 + threadIdx.x;
    double acc = 0.0;
    for (int d = 0; d < 512; ++d) {
        double v = (double)cbF[(size_t)d * 512 + k];
        acc += v * v;
    }
    w2[k] = (float)acc;
}

// ---------------------------------------------------------------------------
// U[k][c*16+u*4+v] = sum_d cbF[d][k]*cWd[c][d][3-u][3-v] + cbd[c]
// ---------------------------------------------------------------------------
__global__ __launch_bounds__(256) void k_udec(
        const float* __restrict__ cbF, const float* __restrict__ cWd,
        const float* __restrict__ cbd, float* __restrict__ U) {
    const int t = threadIdx.x;
    const int k = blockIdx.x * 16 + (t >> 4);
    const int j = t & 15;
    const int u = (j >> 2) & 3, v = j & 3;
    int woff[3];
    #pragma unroll
    for (int m = 0; m < 3; ++m)
        woff[m] = m * 8192 + (3 - u) * 4 + (3 - v);   // Wd flat = c*8192 + d*16 + r*4 + s
    float a0 = 0.f, a1 = 0.f, a2 = 0.f;
    for (int d = 0; d < 512; ++d) {
        float cw = cbF[(size_t)d * 512 + k];
        a0 = fmaf(cw, cWd[woff[0] + d * 16], a0);
        a1 = fmaf(cw, cWd[woff[1] + d * 16], a1);
        a2 = fmaf(cw, cWd[woff[2] + d * 16], a2);
    }
    U[k * 48 +  0 + j] = a0 + cbd[0];
    U[k * 48 + 16 + j] = a1 + cbd[1];
    U[k * 48 + 32 + j] = a2 + cbd[2];
}

// ---------------------------------------------------------------------------
// Encoder: stride-4 4x4 VALID conv + bias + ReLU, chunk of CHUNK positions.
// ---------------------------------------------------------------------------
__global__ __launch_bounds__(512) void k_encode(
        const void* __restrict__ x, const float* __restrict__ cWe,
        const float* __restrict__ cbe, const int* __restrict__ flagp,
        float* __restrict__ zbuf, int P0base) {
    __shared__ float patch[64][48];
    const int flag = *flagp;
    const int t = threadIdx.x;
    const int P0loc = blockIdx.x * 64;

    for (int e = t; e < 3072; e += 512) {
        int pid = e / 48, kk = e % 48;
        int c = kk >> 4, r = (kk >> 2) & 3, s = kk & 3;
        int pos = P0base + P0loc + pid;
        int b = pos >> 10, sp = pos & 1023, i = sp >> 5, j = sp & 31;
        int ga = ((b * 3 + c) * 128 + (i * 4 + r)) * 128 + (j * 4 + s);
        patch[pid][kk] = ldin(x, ga, flag);
    }
    const int d = t;
    float w[48];
    const float4* wv = reinterpret_cast<const float4*>(cWe + (size_t)d * 48);
    #pragma unroll
    for (int i = 0; i < 12; ++i) {
        float4 q = wv[i];
        w[4*i+0] = q.x; w[4*i+1] = q.y; w[4*i+2] = q.z; w[4*i+3] = q.w;
    }
    const float bias = cbe[d];
    __syncthreads();

    for (int p = 0; p < 64; ++p) {
        const float4* pr = reinterpret_cast<const float4*>(patch[p]);
        float acc = bias;
        #pragma unroll
        for (int q4 = 0; q4 < 12; ++q4) {
            float4 v = pr[q4];
            acc = fmaf(v.x, w[4*q4+0], acc);
            acc = fmaf(v.y, w[4*q4+1], acc);
            acc = fmaf(v.z, w[4*q4+2], acc);
            acc = fmaf(v.w, w[4*q4+3], acc);
        }
        zbuf[(size_t)(P0loc + p) * 512 + d] = fmaxf(acc, 0.f);
    }
}

// ---------------------------------------------------------------------------
// Distance partial argmin: fp32 VALU GEMM, tile 64 pos x 128 k, vectorized
// staging from canonical cbF. score = w2[k] - 2*(z.w_k).
// ---------------------------------------------------------------------------
__global__ __launch_bounds__(256) void k_dist(
        const float* __restrict__ zbuf, const float* __restrict__ cbF,
        const float* __restrict__ w2, float* __restrict__ partS,
        int* __restrict__ partI) {
    __shared__ float zl[64][68];
    __shared__ float cbl[64][132];
    __shared__ float redS[64][17];
    __shared__ int   redI[64][17];

    const int t  = threadIdx.x;
    const int tx = t & 15;
    const int ty = t >> 4;
    const int P0 = blockIdx.x * 64;
    const int K0 = blockIdx.y * 128;

    float accs[4][8];
    #pragma unroll
    for (int i = 0; i < 4; ++i)
        #pragma unroll
        for (int j = 0; j < 8; ++j) accs[i][j] = 0.f;

    for (int dc = 0; dc < 512; dc += 64) {
        #pragma unroll
        for (int it = 0; it < 4; ++it) {
            int pi = (t & 15) + 16 * it;
            int dr = (t >> 4) * 4;
            float4 g = *reinterpret_cast<const float4*>(
                &zbuf[(size_t)(P0 + pi) * 512 + dc + dr]);
            zl[dr + 0][pi] = g.x; zl[dr + 1][pi] = g.y;
            zl[dr + 2][pi] = g.z; zl[dr + 3][pi] = g.w;
        }
        #pragma unroll
        for (int it = 0; it < 8; ++it) {
            int row = (t >> 5) + 8 * it;
            int col = (t & 31) * 4;
            float4 f = *reinterpret_cast<const float4*>(
                &cbF[(size_t)(dc + row) * 512 + K0 + col]);
            *reinterpret_cast<float4*>(&cbl[row][col]) = f;
        }
        __syncthreads();

        #pragma unroll 4
        for (int dd = 0; dd < 64; ++dd) {
            float4 zv = *reinterpret_cast<const float4*>(&zl[dd][ty * 4]);
            float4 b0 = *reinterpret_cast<const float4*>(&cbl[dd][tx * 4]);
            float4 b1 = *reinterpret_cast<const float4*>(&cbl[dd][64 + tx * 4]);
            float zr[4] = {zv.x, zv.y, zv.z, zv.w};
            float br[8] = {b0.x, b0.y, b0.z, b0.w, b1.x, b1.y, b1.z, b1.w};
            #pragma unroll
            for (int i = 0; i < 4; ++i)
                #pragma unroll
                for (int j = 0; j < 8; ++j)
                    accs[i][j] = fmaf(zr[i], br[j], accs[i][j]);
        }
        __syncthreads();
    }

    float w2g[8];
    #pragma unroll
    for (int j = 0; j < 8; ++j)
        w2g[j] = w2[K0 + tx * 4 + (j & 3) + (j >> 2) * 64];

    #pragma unroll
    for (int i = 0; i < 4; ++i) {
        float bs = 1e30f; int bk = 511;
        #pragma unroll
        for (int j = 0; j < 8; ++j) {
            int k = K0 + tx * 4 + (j & 3) + (j >> 2) * 64;
            float s = w2g[j] - 2.f * accs[i][j];
            if (s < bs || (s == bs && k < bk)) { bs = s; bk = k; }
        }
        redS[ty * 4 + i][tx] = bs;
        redI[ty * 4 + i][tx] = bk;
    }
    __syncthreads();

    if (t < 64) {
        float bs = redS[t][0]; int bk = redI[t][0];
        for (int q = 1; q < 16; ++q) {
            float s = redS[t][q]; int k = redI[t][q];
            if (s < bs || (s == bs && k < bk)) { bs = s; bk = k; }
        }
        partS[blockIdx.y * CHUNK + P0 + t] = bs;
        partI[blockIdx.y * CHUNK + P0 + t] = bk;
    }
}

// ---------------------------------------------------------------------------
__global__ void k_combine(const float* __restrict__ partS,
                          const int* __restrict__ partI, int* __restrict__ idx,
                          int P0base) {
    int p = blockIdx.x * 256 + threadIdx.x;
    float bs = partS[p]; int bk = partI[p];
    #pragma unroll
    for (int kt = 1; kt < 4; ++kt) {
        float s = partS[kt * CHUNK + p];
        int   k = partI[kt * CHUNK + p];
        if (s < bs || (s == bs && k < bk)) { bs = s; bk = k; }
    }
    idx[P0base + p] = bk & 511;
}

// ---------------------------------------------------------------------------
// z_e output: fp32, (B,512,32,32) d-major, LDS transpose.
// ---------------------------------------------------------------------------
__global__ __launch_bounds__(256) void k_outz(
        const float* __restrict__ zbuf, float* __restrict__ out_z, int P0base) {
    __shared__ float tz[64][65];
    const int t = threadIdx.x;
    const int P0loc = blockIdx.x * 64;
    const int P0g = P0base + P0loc;
    const int D0 = blockIdx.y * 64;

    for (int it = 0; it < 16; ++it) {
        int pi = (t >> 6) + 4 * it;
        int dl = t & 63;
        tz[dl][pi] = zbuf[(size_t)(P0loc + pi) * 512 + D0 + dl];
    }
    __syncthreads();
    const int b = P0g >> 10, SP0 = P0g & 1023;
    for (int it = 0; it < 16; ++it) {
        int row = (t >> 6) + 4 * it;
        int pl = t & 63;
        out_z[((size_t)(b * 512 + D0 + row)) * 1024 + SP0 + pl] = tz[row][pl];
    }
}

// ---------------------------------------------------------------------------
// emb = cbT[idx[pos]][:] in (B,512,32,32) layout. grid 512 blocks: each block
// one (b, 64-sp) slice x all 512 d. Per-thread gather row is FIXED -> 32
// contiguous float4 loads (cbT is 1 MB, L2-resident); writes coalesced over
// 64 sp lanes. Skips scratch tail (b==31 && d>=448) -> k_fixup.
// ---------------------------------------------------------------------------
__global__ __launch_bounds__(256) void k_emb(
        const float* __restrict__ cbT, const int* __restrict__ idx,
        float* __restrict__ out_e) {
    __shared__ int ii[64];
    const int t = threadIdx.x;
    const int b = blockIdx.x >> 4;
    const int SP0 = (blockIdx.x & 15) * 64;
    if (t < 64) ii[t] = idx[b * 1024 + SP0 + t] & 511;
    __syncthreads();
    const int tx = t & 63;          // sp lane
    const int ty = t >> 6;          // d strip (0..3)
    const float* row = cbT + (size_t)ii[tx] * 512;
    const size_t obase = ((size_t)b * 512) * 1024 + SP0 + tx;
    for (int d0 = ty * 128; d0 < ty * 128 + 128; d0 += 4) {
        if (b == 31 && d0 >= 448) break;
        float4 v = *reinterpret_cast<const float4*>(row + d0);
        size_t a = obase + (size_t)d0 * 1024;
        out_e[a         ] = v.x;
        out_e[a + 1024  ] = v.y;
        out_e[a + 2048  ] = v.z;
        out_e[a + 3072  ] = v.w;
    }
}

// ---------------------------------------------------------------------------
// recon = sigmoid(U[idx[pos]]) scattered into (B,3,128,128), fp32.
// Runs AFTER k_emb (overwrites cbT living in out_r).
// ---------------------------------------------------------------------------
__global__ __launch_bounds__(256) void k_recon(
        const float* __restrict__ U, const int* __restrict__ idx,
        float* __restrict__ out_r) {
    const int pos = blockIdx.x * 256 + threadIdx.x;
    const int id = idx[pos] & 511;
    const int b = pos >> 10, sp = pos & 1023, i = sp >> 5, j = sp & 31;
    const float* u = &U[(size_t)id * 48];
    #pragma unroll
    for (int c = 0; c < 3; ++c) {
        #pragma unroll
        for (int uu = 0; uu < 4; ++uu) {
            float4 q = *reinterpret_cast<const float4*>(&u[c * 16 + uu * 4]);
            float4 o;
            o.x = 1.f / (1.f + __expf(-q.x));
            o.y = 1.f / (1.f + __expf(-q.y));
            o.z = 1.f / (1.f + __expf(-q.z));
            o.w = 1.f / (1.f + __expf(-q.w));
            size_t a = ((size_t)((b * 3 + c) * 128) + (i * 4 + uu)) * 128 + j * 4;
            *reinterpret_cast<float4*>(&out_r[a]) = o;
        }
    }
}

// ---------------------------------------------------------------------------
// Fixup: emb for the scratch tail (b=31, d in [448,512)). Single block; stages
// idx+flag into LDS BEFORE writes (writes clobber that storage). cb branchy.
// ---------------------------------------------------------------------------
__global__ __launch_bounds__(256) void k_fixup(
        const void* __restrict__ cb, const int* __restrict__ flagp,
        const int* __restrict__ idx, float* __restrict__ out_e) {
    __shared__ int ii[1024];
    __shared__ int sflag;
    const int t = threadIdx.x;
    if (t == 0) sflag = *flagp;
    for (int e = t; e < 1024; e += 256) ii[e] = idx[31744 + e] & 511;
    __syncthreads();
    const int flag = sflag;
    for (int e = t; e < 65536; e += 256) {
        int d = 448 + (e >> 10), sp = e & 1023;
        out_e[((size_t)(31 * 512 + d)) * 1024 + sp] =
            ldin(cb, (size_t)d * 512 + ii[sp], flag);
    }
}

// ---------------------------------------------------------------------------
extern "C" void kernel_launch(void* const* d_in, const int* in_sizes, int n_in,
                              void* d_out, int out_size, void* d_ws, size_t ws_size,
                              hipStream_t stream) {
    const void* x  = d_in[0];
    const void* We = d_in[1];
    const void* be = d_in[2];
    const void* Wd = d_in[3];
    const void* bd = d_in[4];
    const void* cb = d_in[5];

    float* out   = (float*)d_out;
    float* out_r = out;                       // 1,572,864 fp32
    float* out_z = out + 1572864;             // 16,777,216 fp32
    float* out_e = out + 18350080;            // 16,777,216 fp32

    // Scratch in out_e region:
    char* Ebase = (char*)out_e;
    float* zbuf  = (float*)(Ebase);                       // 16,777,216 B
    float* partS = (float*)(Ebase + 16777216);            //    131,072 B
    int*   partI = (int*)  (Ebase + 16908288);            //    131,072 B
    float* cbF   = (float*)(Ebase + 17039360);            //  1,048,576 B
    float* cWe   = (float*)(Ebase + 18087936);            //     98,304 B
    float* cbe   = (float*)(Ebase + 18186240);            //      2,048 B
    float* cWd   = (float*)(Ebase + 18188288);            //     98,304 B
    float* cbd   = (float*)(Ebase + 18286592);            //         64 B
    char*  Tbase = Ebase + 66846720;                      // last 262,144 B
    int*   idx   = (int*)  (Tbase);                       //    131,072 B
    float* U     = (float*)(Tbase + 131072);              //     98,304 B
    float* w2    = (float*)(Tbase + 229376);              //      2,048 B
    int*   flag  = (int*)  (Tbase + 231424);              //         64 B
    // cbT in out_r region (dead until k_recon, which runs after k_emb):
    float* cbT   = (float*)out_r;                         //  1,048,576 B

    k_sniff<<<1, 64, 0, stream>>>(cb, flag);
    k_canonW<<<195, 256, 0, stream>>>(We, be, Wd, bd, flag, cWe, cbe, cWd, cbd);
    k_prepcb<<<dim3(8, 8), 256, 0, stream>>>(cb, flag, cbF, cbT);
    k_w2<<<8, 64, 0, stream>>>(cbF, w2);
    k_udec<<<32, 256, 0, stream>>>(cbF, cWd, cbd, U);

    for (int c0 = 0; c0 < NPOS; c0 += CHUNK) {
        k_encode<<<CHUNK / 64, 512, 0, stream>>>(x, cWe, cbe, flag, zbuf, c0);
        k_dist<<<dim3(CHUNK / 64, 4), 256, 0, stream>>>(zbuf, cbF, w2, partS, partI);
        k_combine<<<CHUNK / 256, 256, 0, stream>>>(partS, partI, idx, c0);
        k_outz<<<dim3(CHUNK / 64, 8), 256, 0, stream>>>(zbuf, out_z, c0);
    }

    k_emb<<<512, 256, 0, stream>>>(cbT, idx, out_e);
    k_recon<<<128, 256, 0, stream>>>(U, idx, out_r);
    k_fixup<<<1, 256, 0, stream>>>(cb, flag, idx, out_e);
}

// Round 9
// 526.806 us; speedup vs baseline: 2.1161x; 1.2337x over previous
//
#include <hip/hip_runtime.h>
#include <hip/hip_bf16.h>

// Problem constants: B=32, C=3, H=W=128, D=512, K=512, S=4, HL=32, NPOS=32768
#define NPOS 32768

// OUTPUT = FP32. d_out fp32 layout:
//   out_r [0,1572864) | out_z [1572864,18350080) | out_e [18350080,35127296)
// Scratch: read-mostly tables in out_r (clobbered only by k_recon at the end):
//   cbF 262144 f | cbT 262144 f | cWe 24576 f | cbe 512 f | cWd 24576 f | cbd 3 f
// out_e tail (last 262144 B = b31, d>=448): idx 131072B | U 98304B | w2 2048B | flag
// k_main's fused emb skips (b==31 && d>=448); k_fixup writes that region last.
// Order: sniff -> canonW -> prepcb -> w2 -> udec -> k_main -> recon -> fixup.

static __device__ __forceinline__ float bfu(unsigned short h) {
    return __uint_as_float(((unsigned int)h) << 16);
}
// branchy input read: flag=1 -> bf16, flag=0 -> fp32 (scalar; d_in may be 2B-aligned)
static __device__ __forceinline__ float ldin(const void* p, size_t i, int flag) {
    return flag ? bfu(((const unsigned short*)p)[i]) : ((const float*)p)[i];
}

// ---------------------------------------------------------------------------
// S0: input dtype sniffer on the codebook (N(0,1), 512x512).
// ---------------------------------------------------------------------------
__global__ void k_sniff(const void* __restrict__ cb, int* __restrict__ flag) {
    __shared__ float s[64];
    const int k = threadIdx.x;
    const unsigned short* u = (const unsigned short*)cb;
    float acc = 0.f;
    for (int d = 0; d < 512; ++d) {
        float v = bfu(u[d * 512 + k]);
        acc = fmaf(v, v, acc);
    }
    s[k] = acc;
    __syncthreads();
    if (k == 0) {
        int ok = 1;
        for (int i = 0; i < 64; ++i) {
            float a = s[i];
            if (!(a >= 100.f && a <= 2000.f)) ok = 0;
        }
        *flag = ok;
    }
}

// ---------------------------------------------------------------------------
// Canonicalize encoder/decoder weights to fp32 scratch (flat 49,667 elems).
// ---------------------------------------------------------------------------
__global__ void k_canonW(const void* __restrict__ We, const void* __restrict__ be,
                         const void* __restrict__ Wd, const void* __restrict__ bd,
                         const int* __restrict__ flagp, float* __restrict__ cWe,
                         float* __restrict__ cbe, float* __restrict__ cWd,
                         float* __restrict__ cbd) {
    int e = blockIdx.x * 256 + threadIdx.x;
    const int flag = *flagp;
    if (e < 24576)       cWe[e]         = ldin(We, e, flag);
    else if (e < 25088)  cbe[e - 24576] = ldin(be, e - 24576, flag);
    else if (e < 49664)  cWd[e - 25088] = ldin(Wd, e - 25088, flag);
    else if (e < 49667)  cbd[e - 49664] = ldin(bd, e - 49664, flag);
}

// ---------------------------------------------------------------------------
// Canonicalize codebook: cbF fp32 [d][k]; cbT fp32 [k][d] via LDS transpose.
// ---------------------------------------------------------------------------
__global__ __launch_bounds__(256) void k_prepcb(
        const void* __restrict__ cb, const int* __restrict__ flagp,
        float* __restrict__ cbF, float* __restrict__ cbT) {
    __shared__ float tile[64][65];
    const int flag = *flagp;
    const int D0 = blockIdx.x * 64, K0 = blockIdx.y * 64;
    const int t = threadIdx.x;
    for (int it = 0; it < 16; ++it) {
        int r = (t >> 6) + 4 * it;
        int c = t & 63;
        float v = ldin(cb, (size_t)(D0 + r) * 512 + K0 + c, flag);
        cbF[(size_t)(D0 + r) * 512 + K0 + c] = v;
        tile[r][c] = v;
    }
    __syncthreads();
    for (int it = 0; it < 16; ++it) {
        int r = (t >> 6) + 4 * it;
        int c = t & 63;
        cbT[(size_t)(K0 + r) * 512 + D0 + c] = tile[c][r];
    }
}

// ---------------------------------------------------------------------------
// w2[k] = sum_d cbF[d][k]^2 in double.
// ---------------------------------------------------------------------------
__global__ void k_w2(const float* __restrict__ cbF, float* __restrict__ w2) {
    int k = blockIdx.x * 64 + threadIdx.x;
    double acc = 0.0;
    for (int d = 0; d < 512; ++d) {
        double v = (double)cbF[(size_t)d * 512 + k];
        acc += v * v;
    }
    w2[k] = (float)acc;
}

// ---------------------------------------------------------------------------
// U[k][c*16+u*4+v] = sum_d cbF[d][k]*cWd[c][d][3-u][3-v] + cbd[c]
// ---------------------------------------------------------------------------
__global__ __launch_bounds__(256) void k_udec(
        const float* __restrict__ cbF, const float* __restrict__ cWd,
        const float* __restrict__ cbd, float* __restrict__ U) {
    const int t = threadIdx.x;
    const int k = blockIdx.x * 16 + (t >> 4);
    const int j = t & 15;
    const int u = (j >> 2) & 3, v = j & 3;
    int woff[3];
    #pragma unroll
    for (int m = 0; m < 3; ++m)
        woff[m] = m * 8192 + (3 - u) * 4 + (3 - v);
    float a0 = 0.f, a1 = 0.f, a2 = 0.f;
    for (int d = 0; d < 512; ++d) {
        float cw = cbF[(size_t)d * 512 + k];
        a0 = fmaf(cw, cWd[woff[0] + d * 16], a0);
        a1 = fmaf(cw, cWd[woff[1] + d * 16], a1);
        a2 = fmaf(cw, cWd[woff[2] + d * 16], a2);
    }
    U[k * 48 +  0 + j] = a0 + cbd[0];
    U[k * 48 + 16 + j] = a1 + cbd[1];
    U[k * 48 + 32 + j] = a2 + cbd[2];
}

// ---------------------------------------------------------------------------
// FUSED main: per 64-pos block: conv (into LDS) -> out_z write -> full-K
// distance GEMM -> argmin -> idx + fused emb write.
// LDS: patch 64x48 (12288B) | zl 64x68 (17408B) | cbl 64x132 (33792B) = 63488B.
// Epilogue overlays zl with redS/redI and cbl with ii[].
// ---------------------------------------------------------------------------
__global__ __launch_bounds__(256, 2) void k_main(
        const void* __restrict__ x, const float* __restrict__ cWe,
        const float* __restrict__ cbe, const int* __restrict__ flagp,
        const float* __restrict__ cbF, const float* __restrict__ cbT,
        const float* __restrict__ w2, float* __restrict__ out_z,
        float* __restrict__ out_e, int* __restrict__ idx) {
    __shared__ float smem[15872];
    float* patch = smem;           // [64][48]
    float* zl    = smem + 3072;    // [64][68]
    float* cbl   = smem + 7424;    // [64][132]

    const int t = threadIdx.x;
    const int P0 = blockIdx.x * 64;
    const int b  = P0 >> 10;
    const int SP0 = P0 & 1023;
    const int flag = *flagp;

    // ---- stage x patches once: 64 pos x 48 taps ----
    for (int e = t; e < 3072; e += 256) {
        int pid = e / 48, kk = e % 48;
        int c = kk >> 4, r = (kk >> 2) & 3, s = kk & 3;
        int pos = P0 + pid;
        int bb = pos >> 10, sp = pos & 1023, i = sp >> 5, j = sp & 31;
        int ga = ((bb * 3 + c) * 128 + (i * 4 + r)) * 128 + (j * 4 + s);
        patch[pid * 48 + kk] = ldin(x, ga, flag);
    }

    float accs[4][4][8];
    #pragma unroll
    for (int kt = 0; kt < 4; ++kt)
        #pragma unroll
        for (int i = 0; i < 4; ++i)
            #pragma unroll
            for (int j = 0; j < 8; ++j) accs[kt][i][j] = 0.f;

    const int tx = t & 15, ty = t >> 4;   // GEMM micro-tile roles
    const int cd = t & 63;                // conv: d within chunk
    const int cp = (t >> 6) * 16;         // conv: 16-pos strip

    for (int dc = 0; dc < 512; dc += 64) {
        __syncthreads();   // zl free (prev FMA done); patch ready (1st iter)
        // ---- conv: z[p][dc+cd] for 16 positions, write into zl[cd][p] ----
        {
            const int d = dc + cd;
            float w[48];
            const float4* wv = reinterpret_cast<const float4*>(cWe + (size_t)d * 48);
            #pragma unroll
            for (int i = 0; i < 12; ++i) {
                float4 q = wv[i];
                w[4*i+0] = q.x; w[4*i+1] = q.y; w[4*i+2] = q.z; w[4*i+3] = q.w;
            }
            const float bias = cbe[d];
            for (int p = cp; p < cp + 16; ++p) {
                const float4* pr = reinterpret_cast<const float4*>(patch + p * 48);
                float acc = bias;
                #pragma unroll
                for (int q4 = 0; q4 < 12; ++q4) {
                    float4 v = pr[q4];
                    acc = fmaf(v.x, w[4*q4+0], acc);
                    acc = fmaf(v.y, w[4*q4+1], acc);
                    acc = fmaf(v.z, w[4*q4+2], acc);
                    acc = fmaf(v.w, w[4*q4+3], acc);
                }
                zl[cd * 68 + p] = fmaxf(acc, 0.f);
            }
        }
        #pragma unroll
        for (int kt = 0; kt < 4; ++kt) {
            __syncthreads();  // zl written (kt==0); prev FMA done before cbl overwrite
            if (kt == 0) {
                // coalesced out_z write from zl: 64 d x 64 pos
                #pragma unroll
                for (int it = 0; it < 4; ++it) {
                    int row = (t >> 4) + 16 * it;
                    int col = (t & 15) * 4;
                    *reinterpret_cast<float4*>(
                        &out_z[(size_t)(b * 512 + dc + row) * 1024 + SP0 + col]) =
                        *reinterpret_cast<const float4*>(zl + row * 68 + col);
                }
            }
            // stage cbl: 64 d x 128 k
            #pragma unroll
            for (int it = 0; it < 8; ++it) {
                int row = (t >> 5) + 8 * it;
                int col = (t & 31) * 4;
                float4 f = *reinterpret_cast<const float4*>(
                    &cbF[(size_t)(dc + row) * 512 + kt * 128 + col]);
                *reinterpret_cast<float4*>(cbl + row * 132 + col) = f;
            }
            __syncthreads();
            #pragma unroll 4
            for (int dd = 0; dd < 64; ++dd) {
                float4 zv = *reinterpret_cast<const float4*>(zl + dd * 68 + ty * 4);
                float4 b0 = *reinterpret_cast<const float4*>(cbl + dd * 132 + tx * 4);
                float4 b1 = *reinterpret_cast<const float4*>(cbl + dd * 132 + 64 + tx * 4);
                float zr[4] = {zv.x, zv.y, zv.z, zv.w};
                float br[8] = {b0.x, b0.y, b0.z, b0.w, b1.x, b1.y, b1.z, b1.w};
                #pragma unroll
                for (int i = 0; i < 4; ++i)
                    #pragma unroll
                    for (int j = 0; j < 8; ++j)
                        accs[kt][i][j] = fmaf(zr[i], br[j], accs[kt][i][j]);
            }
        }
    }

    // ---- epilogue: fold scores, per-pos argmin ----
    float bs[4]; int bk[4];
    #pragma unroll
    for (int i = 0; i < 4; ++i) { bs[i] = 1e30f; bk[i] = 511; }
    #pragma unroll
    for (int kt = 0; kt < 4; ++kt)
        #pragma unroll
        for (int j = 0; j < 8; ++j) {
            int k = kt * 128 + tx * 4 + (j & 3) + (j >> 2) * 64;
            float wk = w2[k];
            #pragma unroll
            for (int i = 0; i < 4; ++i) {
                float s = wk - 2.f * accs[kt][i][j];
                if (s < bs[i] || (s == bs[i] && k < bk[i])) { bs[i] = s; bk[i] = k; }
            }
        }
    __syncthreads();   // all FMA zl reads done; safe to overlay
    float* redS = smem + 3072;                 // [64][17]
    int*   redI = (int*)(smem + 3072 + 1088);  // [64][17]
    int*   ii   = (int*)(smem + 7424);         // [64] (cbl region, free now)
    #pragma unroll
    for (int i = 0; i < 4; ++i) {
        int pos = ty * 4 + i;
        redS[pos * 17 + tx] = bs[i];
        redI[pos * 17 + tx] = bk[i];
    }
    __syncthreads();
    if (t < 64) {
        float best = redS[t * 17]; int bidx = redI[t * 17];
        for (int q = 1; q < 16; ++q) {
            float s = redS[t * 17 + q]; int k = redI[t * 17 + q];
            if (s < best || (s == best && k < bidx)) { best = s; bidx = k; }
        }
        bidx &= 511;
        ii[t] = bidx;
        idx[P0 + t] = bidx;
    }
    __syncthreads();

    // ---- fused emb: out_e[b][d][SP0+sp] = cbT[ii[sp]][d] ----
    const int sp = t & 63, dq = t >> 6;
    const float* row = cbT + (size_t)ii[sp] * 512;
    const size_t obase = ((size_t)b * 512) * 1024 + SP0 + sp;
    for (int d0 = dq * 128; d0 < dq * 128 + 128; d0 += 4) {
        if (b == 31 && d0 >= 448) break;   // scratch tail -> k_fixup
        float4 v = *reinterpret_cast<const float4*>(row + d0);
        out_e[obase + (size_t)(d0    ) * 1024] = v.x;
        out_e[obase + (size_t)(d0 + 1) * 1024] = v.y;
        out_e[obase + (size_t)(d0 + 2) * 1024] = v.z;
        out_e[obase + (size_t)(d0 + 3) * 1024] = v.w;
    }
}

// ---------------------------------------------------------------------------
// recon = sigmoid(U[idx[pos]]) scattered into (B,3,128,128), fp32.
// Overwrites out_r scratch (cbF/cbT/weights) — runs after k_main.
// ---------------------------------------------------------------------------
__global__ __launch_bounds__(256) void k_recon(
        const float* __restrict__ U, const int* __restrict__ idx,
        float* __restrict__ out_r) {
    const int pos = blockIdx.x * 256 + threadIdx.x;
    const int id = idx[pos] & 511;
    const int b = pos >> 10, sp = pos & 1023, i = sp >> 5, j = sp & 31;
    const float* u = &U[(size_t)id * 48];
    #pragma unroll
    for (int c = 0; c < 3; ++c) {
        #pragma unroll
        for (int uu = 0; uu < 4; ++uu) {
            float4 q = *reinterpret_cast<const float4*>(&u[c * 16 + uu * 4]);
            float4 o;
            o.x = 1.f / (1.f + __expf(-q.x));
            o.y = 1.f / (1.f + __expf(-q.y));
            o.z = 1.f / (1.f + __expf(-q.z));
            o.w = 1.f / (1.f + __expf(-q.w));
            size_t a = ((size_t)((b * 3 + c) * 128) + (i * 4 + uu)) * 128 + j * 4;
            *reinterpret_cast<float4*>(&out_r[a]) = o;
        }
    }
}

// ---------------------------------------------------------------------------
// Fixup: emb for the scratch tail (b=31, d in [448,512)). Single block; stages
// idx+flag in LDS BEFORE writing (writes clobber that storage). Raw cb reads.
// ---------------------------------------------------------------------------
__global__ __launch_bounds__(256) void k_fixup(
        const void* __restrict__ cb, const int* __restrict__ flagp,
        const int* __restrict__ idx, float* __restrict__ out_e) {
    __shared__ int ii[1024];
    __shared__ int sflag;
    const int t = threadIdx.x;
    if (t == 0) sflag = *flagp;
    for (int e = t; e < 1024; e += 256) ii[e] = idx[31744 + e] & 511;
    __syncthreads();
    const int flag = sflag;
    for (int e = t; e < 65536; e += 256) {
        int d = 448 + (e >> 10), sp = e & 1023;
        out_e[((size_t)(31 * 512 + d)) * 1024 + sp] =
            ldin(cb, (size_t)d * 512 + ii[sp], flag);
    }
}

// ---------------------------------------------------------------------------
extern "C" void kernel_launch(void* const* d_in, const int* in_sizes, int n_in,
                              void* d_out, int out_size, void* d_ws, size_t ws_size,
                              hipStream_t stream) {
    const void* x  = d_in[0];
    const void* We = d_in[1];
    const void* be = d_in[2];
    const void* Wd = d_in[3];
    const void* bd = d_in[4];
    const void* cb = d_in[5];

    float* out   = (float*)d_out;
    float* out_r = out;                       // 1,572,864 fp32
    float* out_z = out + 1572864;             // 16,777,216 fp32
    float* out_e = out + 18350080;            // 16,777,216 fp32

    // Scratch tables in out_r (recon overwrites at the very end):
    float* cbF = out_r;                       // 262144 f
    float* cbT = out_r + 262144;              // 262144 f
    float* cWe = out_r + 524288;              //  24576 f
    float* cbe = out_r + 548864;              //    512 f
    float* cWd = out_r + 549376;              //  24576 f
    float* cbd = out_r + 573952;              //      3 f

    // out_e tail scratch (last 262,144 B):
    char*  Tbase = (char*)out_e + 66846720;
    int*   idx   = (int*)  (Tbase);           // 131,072 B
    float* U     = (float*)(Tbase + 131072);  //  98,304 B
    float* w2    = (float*)(Tbase + 229376);  //   2,048 B
    int*   flag  = (int*)  (Tbase + 231424);  //      64 B

    k_sniff<<<1, 64, 0, stream>>>(cb, flag);
    k_canonW<<<195, 256, 0, stream>>>(We, be, Wd, bd, flag, cWe, cbe, cWd, cbd);
    k_prepcb<<<dim3(8, 8), 256, 0, stream>>>(cb, flag, cbF, cbT);
    k_w2<<<8, 64, 0, stream>>>(cbF, w2);
    k_udec<<<32, 256, 0, stream>>>(cbF, cWd, cbd, U);

    k_main<<<512, 256, 0, stream>>>(x, cWe, cbe, flag, cbF, cbT, w2,
                                    out_z, out_e, idx);

    k_recon<<<128, 256, 0, stream>>>(U, idx, out_r);
    k_fixup<<<1, 256, 0, stream>>>(cb, flag, idx, out_e);
}

// Round 10
// 364.885 us; speedup vs baseline: 3.0552x; 1.4438x over previous
//
#include <hip/hip_runtime.h>
#include <hip/hip_bf16.h>

// B=32, C=3, H=W=128, D=512, K=512, S=4, NPOS=32768
#define NPOS 32768
#define EPS_GAP 4e-3f
#define MAXSUS 4096

typedef __attribute__((ext_vector_type(8))) short short8;
typedef __attribute__((ext_vector_type(4))) float floatx4;

static __device__ __forceinline__ float bfu(unsigned short h) {
    return __uint_as_float(((unsigned int)h) << 16);
}
static __device__ __forceinline__ unsigned short f2bf(float f) {
    unsigned int u = __float_as_uint(f);
    u = (u + 0x7fffu + ((u >> 16) & 1u)) >> 16;   // RNE
    return (unsigned short)u;
}
static __device__ __forceinline__ float ldin(const void* p, size_t i, int flag) {
    return flag ? bfu(((const unsigned short*)p)[i]) : ((const float*)p)[i];
}

// ---------------------------------------------------------------------------
__global__ void k_sniff(const void* __restrict__ cb, int* __restrict__ flag,
                        int* __restrict__ scnt) {
    __shared__ float s[64];
    const int k = threadIdx.x;
    const unsigned short* u = (const unsigned short*)cb;
    float acc = 0.f;
    for (int d = 0; d < 512; ++d) { float v = bfu(u[d * 512 + k]); acc = fmaf(v, v, acc); }
    s[k] = acc;
    __syncthreads();
    if (k == 0) {
        int ok = 1;
        for (int i = 0; i < 64; ++i) { float a = s[i]; if (!(a >= 100.f && a <= 2000.f)) ok = 0; }
        *flag = ok;
        *scnt = 0;
    }
}

// ---------------------------------------------------------------------------
__global__ void k_canonW(const void* __restrict__ We, const void* __restrict__ be,
                         const void* __restrict__ Wd, const void* __restrict__ bd,
                         const int* __restrict__ flagp, float* __restrict__ cWe,
                         float* __restrict__ cbe, float* __restrict__ cWd,
                         float* __restrict__ cbd) {
    int e = blockIdx.x * 256 + threadIdx.x;
    const int flag = *flagp;
    if (e < 24576)       cWe[e]         = ldin(We, e, flag);
    else if (e < 25088)  cbe[e - 24576] = ldin(be, e - 24576, flag);
    else if (e < 49664)  cWd[e - 25088] = ldin(Wd, e - 25088, flag);
    else if (e < 49667)  cbd[e - 49664] = ldin(bd, e - 49664, flag);
}

// ---------------------------------------------------------------------------
// cbF fp32 [d][k]; cbT fp32 [k][d]; cbHT/cbLT bf16-split [k][d].
// ---------------------------------------------------------------------------
__global__ __launch_bounds__(256) void k_prepcb(
        const void* __restrict__ cb, const int* __restrict__ flagp,
        float* __restrict__ cbF, float* __restrict__ cbT,
        unsigned short* __restrict__ cbHT, unsigned short* __restrict__ cbLT) {
    __shared__ float tile[64][65];
    const int flag = *flagp;
    const int D0 = blockIdx.x * 64, K0 = blockIdx.y * 64;
    const int t = threadIdx.x;
    for (int it = 0; it < 16; ++it) {
        int r = (t >> 6) + 4 * it, c = t & 63;
        float v = ldin(cb, (size_t)(D0 + r) * 512 + K0 + c, flag);
        cbF[(size_t)(D0 + r) * 512 + K0 + c] = v;
        tile[r][c] = v;
    }
    __syncthreads();
    for (int it = 0; it < 16; ++it) {
        int r = (t >> 6) + 4 * it, c = t & 63;
        float v = tile[c][r];
        size_t o = (size_t)(K0 + r) * 512 + D0 + c;
        cbT[o] = v;
        unsigned short h = f2bf(v);
        cbHT[o] = h;
        cbLT[o] = f2bf(v - bfu(h));
    }
}

// ---------------------------------------------------------------------------
__global__ void k_w2(const float* __restrict__ cbF, float* __restrict__ w2,
                     double* __restrict__ w2d) {
    int k = blockIdx.x * 64 + threadIdx.x;
    double acc = 0.0;
    for (int d = 0; d < 512; ++d) { double v = (double)cbF[(size_t)d * 512 + k]; acc += v * v; }
    w2[k] = (float)acc;
    w2d[k] = acc;
}

// ---------------------------------------------------------------------------
// U[k][c*16+u*4+v] = sum_d cbF[d][k]*cWd[c][d][3-u][3-v] + cbd[c]
// 128 blocks; wave lanes: j=(lane>>2) (16 outputs), dpart=lane&3; shuffle-reduce.
// ---------------------------------------------------------------------------
__global__ __launch_bounds__(256) void k_udec(
        const float* __restrict__ cbF, const float* __restrict__ cWd,
        const float* __restrict__ cbd, float* __restrict__ U) {
    const int t = threadIdx.x;
    const int k = blockIdx.x * 4 + (t >> 6);
    const int lane = t & 63;
    const int j = lane >> 2, dpart = lane & 3;
    const int u = (j >> 2) & 3, v = j & 3;
    int woff[3];
    #pragma unroll
    for (int m = 0; m < 3; ++m) woff[m] = m * 8192 + (3 - u) * 4 + (3 - v);
    float a0 = 0.f, a1 = 0.f, a2 = 0.f;
    for (int i = 0; i < 128; ++i) {
        int d = dpart * 128 + i;
        float cw = cbF[(size_t)d * 512 + k];
        a0 = fmaf(cw, cWd[woff[0] + d * 16], a0);
        a1 = fmaf(cw, cWd[woff[1] + d * 16], a1);
        a2 = fmaf(cw, cWd[woff[2] + d * 16], a2);
    }
    a0 += __shfl_xor(a0, 1); a0 += __shfl_xor(a0, 2);
    a1 += __shfl_xor(a1, 1); a1 += __shfl_xor(a1, 2);
    a2 += __shfl_xor(a2, 1); a2 += __shfl_xor(a2, 2);
    if (dpart == 0) {
        U[k * 48 +  0 + j] = a0 + cbd[0];
        U[k * 48 + 16 + j] = a1 + cbd[1];
        U[k * 48 + 32 + j] = a2 + cbd[2];
    }
}

// ---------------------------------------------------------------------------
// FUSED main (MFMA): per 64-pos block, d-chunks of 32:
//   conv -> zh/zl bf16 in LDS [pos][d] -> out_z (= zh+zl) -> MFMA dist.
// Waves: wave w owns 4 M-tiles (all 64 pos) x 8 N-tiles (codes w*128..+127).
// Epilogue: best/second-best argmin -> idx + suspects; fused emb from cbT.
// LDS: patch 12288 | zA 5120 | zB 5120 | cbS 40960 = 63488 B.
// ---------------------------------------------------------------------------
__global__ __launch_bounds__(256, 2) void k_main(
        const void* __restrict__ x, const float* __restrict__ cWe,
        const float* __restrict__ cbe, const int* __restrict__ flagp,
        const unsigned short* __restrict__ cbHT, const unsigned short* __restrict__ cbLT,
        const float* __restrict__ cbT, const float* __restrict__ w2,
        float* __restrict__ out_z, float* __restrict__ out_e,
        int* __restrict__ idx, int* __restrict__ scnt, int* __restrict__ spos,
        int skipTail) {
    __shared__ __align__(16) char smc[63488];
    float* patch = (float*)smc;                          // [64][48] fp32
    unsigned short* zA = (unsigned short*)(smc + 12288); // [64][40] bf16 hi
    unsigned short* zB = (unsigned short*)(smc + 17408); // [64][40] bf16 lo
    unsigned short* cbS = (unsigned short*)(smc + 22528);// [512][40] bf16

    const int t = threadIdx.x;
    const int P0 = blockIdx.x * 64;
    const int b = P0 >> 10, SP0 = P0 & 1023;
    const int flag = *flagp;
    const int wave = t >> 6, lane = t & 63;
    const int quad = lane >> 4, lcol = lane & 15;

    // stage x patches once
    for (int e = t; e < 3072; e += 256) {
        int pid = e / 48, kk = e % 48;
        int c = kk >> 4, r = (kk >> 2) & 3, s = kk & 3;
        int pos = P0 + pid;
        int bb = pos >> 10, sp = pos & 1023, i = sp >> 5, j = sp & 31;
        patch[pid * 48 + kk] = ldin(x, ((bb * 3 + c) * 128 + (i * 4 + r)) * 128 + (j * 4 + s), flag);
    }

    floatx4 acc[4][8];
    #pragma unroll
    for (int mt = 0; mt < 4; ++mt)
        #pragma unroll
        for (int j = 0; j < 8; ++j) acc[mt][j] = (floatx4){0.f, 0.f, 0.f, 0.f};

    const int cd = t & 31;          // conv: d within chunk
    const int ps = (t >> 5) * 8;    // conv: 8-pos strip

    for (int dc = 0; dc < 512; dc += 32) {
        __syncthreads();   // zA/zB/cbS free; patch ready (1st iter)
        // ---- conv for (dc+cd, ps..ps+7) ----
        {
            const float4* wv = (const float4*)(cWe + (size_t)(dc + cd) * 48);
            const float bias = cbe[dc + cd];
            float za[8];
            #pragma unroll
            for (int p = 0; p < 8; ++p) za[p] = bias;
            #pragma unroll
            for (int q4 = 0; q4 < 12; ++q4) {
                float4 wq = wv[q4];
                #pragma unroll
                for (int p = 0; p < 8; ++p) {
                    float4 v = ((const float4*)(patch + (ps + p) * 48))[q4];
                    za[p] = fmaf(v.x, wq.x, za[p]);
                    za[p] = fmaf(v.y, wq.y, za[p]);
                    za[p] = fmaf(v.z, wq.z, za[p]);
                    za[p] = fmaf(v.w, wq.w, za[p]);
                }
            }
            #pragma unroll
            for (int p = 0; p < 8; ++p) {
                float z = fmaxf(za[p], 0.f);
                unsigned short h = f2bf(z);
                zA[(ps + p) * 40 + cd] = h;
                zB[(ps + p) * 40 + cd] = f2bf(z - bfu(h));
            }
        }
        // ---- stage cbH chunk: [512 codes][32 d] ----
        #pragma unroll
        for (int cc = 0; cc < 2; ++cc) {
            int code = t + cc * 256;
            const uint4* src = (const uint4*)((const char*)cbHT + (size_t)code * 1024 + dc * 2);
            uint4* dst = (uint4*)((char*)cbS + code * 80);
            #pragma unroll
            for (int i = 0; i < 4; ++i) dst[i] = src[i];
        }
        __syncthreads();
        // ---- out_z = zh + zl (coalesced) ----
        #pragma unroll
        for (int i = 0; i < 8; ++i) {
            int row = (t >> 6) + 4 * i, col = t & 63;
            float vz = bfu(zA[col * 40 + row]) + bfu(zB[col * 40 + row]);
            out_z[(size_t)(b * 512 + dc + row) * 1024 + SP0 + col] = vz;
        }
        // ---- MFMA: 4 M-tiles x 8 N-tiles ----
        short8 aH[4], aL[4];
        #pragma unroll
        for (int mt = 0; mt < 4; ++mt) {
            aH[mt] = *(const short8*)((char*)zA + (mt * 16 + lcol) * 80 + quad * 16);
            aL[mt] = *(const short8*)((char*)zB + (mt * 16 + lcol) * 80 + quad * 16);
        }
        #pragma unroll
        for (int j = 0; j < 8; ++j) {
            int code = (wave * 8 + j) * 16 + lcol;
            short8 bH = *(const short8*)((char*)cbS + code * 80 + quad * 16);
            #pragma unroll
            for (int mt = 0; mt < 4; ++mt) {
                acc[mt][j] = __builtin_amdgcn_mfma_f32_16x16x32_bf16(aH[mt], bH, acc[mt][j], 0, 0, 0);
                acc[mt][j] = __builtin_amdgcn_mfma_f32_16x16x32_bf16(aL[mt], bH, acc[mt][j], 0, 0, 0);
            }
        }
        if (!flag) {   // fp32 inputs: third term zh*cbL
            __syncthreads();
            #pragma unroll
            for (int cc = 0; cc < 2; ++cc) {
                int code = t + cc * 256;
                const uint4* src = (const uint4*)((const char*)cbLT + (size_t)code * 1024 + dc * 2);
                uint4* dst = (uint4*)((char*)cbS + code * 80);
                #pragma unroll
                for (int i = 0; i < 4; ++i) dst[i] = src[i];
            }
            __syncthreads();
            #pragma unroll
            for (int j = 0; j < 8; ++j) {
                int code = (wave * 8 + j) * 16 + lcol;
                short8 bL = *(const short8*)((char*)cbS + code * 80 + quad * 16);
                #pragma unroll
                for (int mt = 0; mt < 4; ++mt)
                    acc[mt][j] = __builtin_amdgcn_mfma_f32_16x16x32_bf16(aH[mt], bL, acc[mt][j], 0, 0, 0);
            }
        }
    }

    // ---- epilogue: per-lane best/second over its 8 codes x 16 pos ----
    float s1[4][4], s2[4][4]; int k1[4][4];
    #pragma unroll
    for (int mt = 0; mt < 4; ++mt)
        #pragma unroll
        for (int r = 0; r < 4; ++r) { s1[mt][r] = 1e30f; s2[mt][r] = 1e30f; k1[mt][r] = 511; }
    #pragma unroll
    for (int j = 0; j < 8; ++j) {
        int code = (wave * 8 + j) * 16 + lcol;
        float wk = w2[code];
        #pragma unroll
        for (int mt = 0; mt < 4; ++mt)
            #pragma unroll
            for (int r = 0; r < 4; ++r) {
                float s = wk - 2.f * acc[mt][j][r];
                if (s < s1[mt][r]) { s2[mt][r] = s1[mt][r]; s1[mt][r] = s; k1[mt][r] = code; }
                else { if (s < s2[mt][r]) s2[mt][r] = s;
                       if (s == s1[mt][r] && code < k1[mt][r]) k1[mt][r] = code; }
            }
    }
    __syncthreads();
    float* redS  = (float*)smc;             // [64][65]
    int*   redI  = (int*)(smc + 16640);     // [64][65]
    float* redS2 = (float*)(smc + 33280);   // [64][65]
    int*   ii    = (int*)(smc + 49920);     // [64]
    #pragma unroll
    for (int mt = 0; mt < 4; ++mt)
        #pragma unroll
        for (int r = 0; r < 4; ++r) {
            int pos = mt * 16 + quad * 4 + r;
            int col = wave * 16 + lcol;
            redS[pos * 65 + col]  = s1[mt][r];
            redI[pos * 65 + col]  = k1[mt][r];
            redS2[pos * 65 + col] = s2[mt][r];
        }
    __syncthreads();
    if (t < 64) {
        float b1 = 1e30f, b2 = 1e30f; int bk = 511;
        for (int q = 0; q < 64; ++q) {
            float es1 = redS[t * 65 + q], es2 = redS2[t * 65 + q];
            int   ek  = redI[t * 65 + q];
            if (es1 < b1) { b2 = fminf(b1, es2); b1 = es1; bk = ek; }
            else { if (es1 < b2) b2 = es1;
                   if (es1 == b1) { b2 = b1; if (ek < bk) bk = ek; }
                   if (es2 < b2) b2 = es2; }
        }
        bk &= 511;
        ii[t] = bk;
        idx[P0 + t] = bk;
        if (b2 - b1 < EPS_GAP) {
            int slot = atomicAdd(scnt, 1);
            if (slot < MAXSUS) spos[slot] = P0 + t;
        }
    }
    __syncthreads();

    // ---- fused emb ----
    const int sp = t & 63, dq = t >> 6;
    const float* row = cbT + (size_t)ii[sp] * 512;
    const size_t obase = ((size_t)b * 512) * 1024 + SP0 + sp;
    for (int d0 = dq * 128; d0 < dq * 128 + 128; d0 += 4) {
        if (skipTail && b == 31 && d0 >= 448) break;
        float4 v = *(const float4*)(row + d0);
        out_e[obase + (size_t)(d0    ) * 1024] = v.x;
        out_e[obase + (size_t)(d0 + 1) * 1024] = v.y;
        out_e[obase + (size_t)(d0 + 2) * 1024] = v.z;
        out_e[obase + (size_t)(d0 + 3) * 1024] = v.w;
    }
}

// ---------------------------------------------------------------------------
// Exact fp64 rescore of suspect positions; patches idx and emb column.
// ---------------------------------------------------------------------------
__global__ __launch_bounds__(256) void k_rescore(
        const float* __restrict__ out_z, const float* __restrict__ cbT,
        const double* __restrict__ w2d, int* __restrict__ idx,
        const int* __restrict__ scnt, const int* __restrict__ spos,
        float* __restrict__ out_e, int skipTail) {
    __shared__ float zsh[512];
    __shared__ float rs[256];
    __shared__ int rk[256];
    __shared__ int bc[2];
    const int t = threadIdx.x;
    int n = *scnt; if (n > MAXSUS) n = MAXSUS;
    for (int s = blockIdx.x; s < n; s += gridDim.x) {
        int p = spos[s] & 32767;
        int b = p >> 10, sp = p & 1023;
        __syncthreads();
        zsh[t]       = out_z[(size_t)(b * 512 + t) * 1024 + sp];
        zsh[t + 256] = out_z[(size_t)(b * 512 + t + 256) * 1024 + sp];
        __syncthreads();
        float bs = 1e30f; int bk = 511;
        for (int cc = 0; cc < 2; ++cc) {
            int k = t + cc * 256;
            double a = 0.0;
            const float* row = cbT + (size_t)k * 512;
            for (int d = 0; d < 512; ++d) a = fma((double)zsh[d], (double)row[d], a);
            float sc = (float)(w2d[k] - 2.0 * a);
            if (sc < bs || (sc == bs && k < bk)) { bs = sc; bk = k; }
        }
        rs[t] = bs; rk[t] = bk;
        __syncthreads();
        for (int str = 128; str > 0; str >>= 1) {
            if (t < str) {
                float so = rs[t + str]; int ko = rk[t + str];
                if (so < rs[t] || (so == rs[t] && ko < rk[t])) { rs[t] = so; rk[t] = ko; }
            }
            __syncthreads();
        }
        if (t == 0) {
            int kstar = rk[0] & 511;
            int old = idx[p] & 511;
            bc[0] = kstar; bc[1] = (kstar != old);
            idx[p] = kstar;
        }
        __syncthreads();
        if (bc[1]) {
            int kk = bc[0];
            for (int d = t; d < 512; d += 256) {
                if (skipTail && b == 31 && d >= 448) continue;
                out_e[(size_t)(b * 512 + d) * 1024 + sp] = cbT[(size_t)kk * 512 + d];
            }
        }
    }
}

// ---------------------------------------------------------------------------
__global__ __launch_bounds__(256) void k_recon(
        const float* __restrict__ U, const int* __restrict__ idx,
        float* __restrict__ out_r) {
    const int pos = blockIdx.x * 256 + threadIdx.x;
    const int id = idx[pos] & 511;
    const int b = pos >> 10, sp = pos & 1023, i = sp >> 5, j = sp & 31;
    const float* u = &U[(size_t)id * 48];
    #pragma unroll
    for (int c = 0; c < 3; ++c)
        #pragma unroll
        for (int uu = 0; uu < 4; ++uu) {
            float4 q = *(const float4*)(&u[c * 16 + uu * 4]);
            float4 o;
            o.x = 1.f / (1.f + __expf(-q.x));
            o.y = 1.f / (1.f + __expf(-q.y));
            o.z = 1.f / (1.f + __expf(-q.z));
            o.w = 1.f / (1.f + __expf(-q.w));
            *(float4*)(&out_r[((size_t)((b * 3 + c) * 128) + (i * 4 + uu)) * 128 + j * 4]) = o;
        }
}

// ---------------------------------------------------------------------------
// Tail fixup (only when tail lives inside out_e): b=31, d in [448,512).
// Single 1024-thread block; stages idx slice + flag before writing.
// ---------------------------------------------------------------------------
__global__ __launch_bounds__(1024) void k_fixup(
        const void* __restrict__ cb, const int* __restrict__ flagp,
        const int* __restrict__ idx, float* __restrict__ out_e) {
    __shared__ int ii[1024];
    __shared__ int sflag;
    const int t = threadIdx.x;
    if (t == 0) sflag = *flagp;
    ii[t] = idx[31744 + t] & 511;
    __syncthreads();
    const int flag = sflag;
    for (int e = t; e < 65536; e += 1024) {
        int d = 448 + (e >> 10), sp = e & 1023;
        out_e[((size_t)(31 * 512 + d)) * 1024 + sp] = ldin(cb, (size_t)d * 512 + ii[sp], flag);
    }
}

// ---------------------------------------------------------------------------
extern "C" void kernel_launch(void* const* d_in, const int* in_sizes, int n_in,
                              void* d_out, int out_size, void* d_ws, size_t ws_size,
                              hipStream_t stream) {
    const void* x  = d_in[0];
    const void* We = d_in[1];
    const void* be = d_in[2];
    const void* Wd = d_in[3];
    const void* bd = d_in[4];
    const void* cb = d_in[5];

    float* out   = (float*)d_out;
    float* out_r = out;                       // 1,572,864 fp32 (6.29 MB)
    float* out_z = out + 1572864;             // 16,777,216 fp32
    float* out_e = out + 18350080;            // 16,777,216 fp32

    // Read-mostly tables in out_r (recon overwrites at the very end):
    char* Rb = (char*)out_r;
    float* cbF          = (float*)(Rb);                  // 1,048,576 B
    float* cbT          = (float*)(Rb + 1048576);        // 1,048,576 B
    float* cWe          = (float*)(Rb + 2097152);        //    98,304 B
    float* cbe          = (float*)(Rb + 2195456);        //     2,048 B
    float* cWd          = (float*)(Rb + 2197504);        //    98,304 B
    float* cbd          = (float*)(Rb + 2295808);        //        64 B
    unsigned short* cbHT= (unsigned short*)(Rb + 2295872); // 524,288 B
    unsigned short* cbLT= (unsigned short*)(Rb + 2820160); // 524,288 B

    // Tail scratch: prefer d_ws; else last 256 KB of out_e (fixup required).
    int tailWS = (ws_size >= 262144) ? 1 : 0;
    char* Tbase = tailWS ? (char*)d_ws : ((char*)out_e + 66846720);
    int skipTail = tailWS ? 0 : 1;
    int*    idx  = (int*)   (Tbase);            // 131,072 B
    float*  U    = (float*) (Tbase + 131072);   //  98,304 B
    float*  w2   = (float*) (Tbase + 229376);   //   2,048 B
    double* w2d  = (double*)(Tbase + 231424);   //   4,096 B
    int*    flag = (int*)   (Tbase + 235520);   //      64 B
    int*    scnt = (int*)   (Tbase + 235584);   //      64 B
    int*    spos = (int*)   (Tbase + 235648);   //  16,384 B

    k_sniff<<<1, 64, 0, stream>>>(cb, flag, scnt);
    k_canonW<<<195, 256, 0, stream>>>(We, be, Wd, bd, flag, cWe, cbe, cWd, cbd);
    k_prepcb<<<dim3(8, 8), 256, 0, stream>>>(cb, flag, cbF, cbT, cbHT, cbLT);
    k_w2<<<8, 64, 0, stream>>>(cbF, w2, w2d);
    k_udec<<<128, 256, 0, stream>>>(cbF, cWd, cbd, U);

    k_main<<<512, 256, 0, stream>>>(x, cWe, cbe, flag, cbHT, cbLT, cbT, w2,
                                    out_z, out_e, idx, scnt, spos, skipTail);

    k_rescore<<<128, 256, 0, stream>>>(out_z, cbT, w2d, idx, scnt, spos, out_e, skipTail);
    k_recon<<<128, 256, 0, stream>>>(U, idx, out_r);
    if (skipTail)
        k_fixup<<<1, 1024, 0, stream>>>(cb, flag, idx, out_e);
}

// Round 11
// 363.200 us; speedup vs baseline: 3.0694x; 1.0046x over previous
//
#include <hip/hip_runtime.h>
#include <hip/hip_bf16.h>

// B=32, C=3, H=W=128, D=512, K=512, S=4, NPOS=32768
#define NPOS 32768
#define EPS_GAP 4e-3f
#define MAXSUS 4096

typedef __attribute__((ext_vector_type(8))) short short8;
typedef __attribute__((ext_vector_type(4))) float floatx4;

static __device__ __forceinline__ float bfu(unsigned short h) {
    return __uint_as_float(((unsigned int)h) << 16);
}
static __device__ __forceinline__ unsigned short f2bf(float f) {
    unsigned int u = __float_as_uint(f);
    u = (u + 0x7fffu + ((u >> 16) & 1u)) >> 16;   // RNE
    return (unsigned short)u;
}
static __device__ __forceinline__ float ldin(const void* p, size_t i, int flag) {
    return flag ? bfu(((const unsigned short*)p)[i]) : ((const float*)p)[i];
}

// ---------------------------------------------------------------------------
__global__ void k_sniff(const void* __restrict__ cb, int* __restrict__ flag,
                        int* __restrict__ scnt) {
    __shared__ float s[64];
    const int k = threadIdx.x;
    const unsigned short* u = (const unsigned short*)cb;
    float acc = 0.f;
    for (int d = 0; d < 512; ++d) { float v = bfu(u[d * 512 + k]); acc = fmaf(v, v, acc); }
    s[k] = acc;
    __syncthreads();
    if (k == 0) {
        int ok = 1;
        for (int i = 0; i < 64; ++i) { float a = s[i]; if (!(a >= 100.f && a <= 2000.f)) ok = 0; }
        *flag = ok;
        *scnt = 0;
    }
}

// ---------------------------------------------------------------------------
__global__ void k_canonW(const void* __restrict__ We, const void* __restrict__ be,
                         const void* __restrict__ Wd, const void* __restrict__ bd,
                         const int* __restrict__ flagp, float* __restrict__ cWe,
                         float* __restrict__ cbe, float* __restrict__ cWd,
                         float* __restrict__ cbd) {
    int e = blockIdx.x * 256 + threadIdx.x;
    const int flag = *flagp;
    if (e < 24576)       cWe[e]         = ldin(We, e, flag);
    else if (e < 25088)  cbe[e - 24576] = ldin(be, e - 24576, flag);
    else if (e < 49664)  cWd[e - 25088] = ldin(Wd, e - 25088, flag);
    else if (e < 49667)  cbd[e - 49664] = ldin(bd, e - 49664, flag);
}

// ---------------------------------------------------------------------------
// cbF fp32 [d][k]; cbT fp32 [k][d]; cbHT/cbLT bf16-split [k][d].
// ---------------------------------------------------------------------------
__global__ __launch_bounds__(256) void k_prepcb(
        const void* __restrict__ cb, const int* __restrict__ flagp,
        float* __restrict__ cbF, float* __restrict__ cbT,
        unsigned short* __restrict__ cbHT, unsigned short* __restrict__ cbLT) {
    __shared__ float tile[64][65];
    const int flag = *flagp;
    const int D0 = blockIdx.x * 64, K0 = blockIdx.y * 64;
    const int t = threadIdx.x;
    for (int it = 0; it < 16; ++it) {
        int r = (t >> 6) + 4 * it, c = t & 63;
        float v = ldin(cb, (size_t)(D0 + r) * 512 + K0 + c, flag);
        cbF[(size_t)(D0 + r) * 512 + K0 + c] = v;
        tile[r][c] = v;
    }
    __syncthreads();
    for (int it = 0; it < 16; ++it) {
        int r = (t >> 6) + 4 * it, c = t & 63;
        float v = tile[c][r];
        size_t o = (size_t)(K0 + r) * 512 + D0 + c;
        cbT[o] = v;
        unsigned short h = f2bf(v);
        cbHT[o] = h;
        cbLT[o] = f2bf(v - bfu(h));
    }
}

// ---------------------------------------------------------------------------
__global__ void k_w2(const float* __restrict__ cbF, float* __restrict__ w2,
                     double* __restrict__ w2d) {
    int k = blockIdx.x * 64 + threadIdx.x;
    double acc = 0.0;
    for (int d = 0; d < 512; ++d) { double v = (double)cbF[(size_t)d * 512 + k]; acc += v * v; }
    w2[k] = (float)acc;
    w2d[k] = acc;
}

// ---------------------------------------------------------------------------
// U[k][c*16+u*4+v] = sum_d cbF[d][k]*cWd[c][d][3-u][3-v] + cbd[c]
// ---------------------------------------------------------------------------
__global__ __launch_bounds__(256) void k_udec(
        const float* __restrict__ cbF, const float* __restrict__ cWd,
        const float* __restrict__ cbd, float* __restrict__ U) {
    const int t = threadIdx.x;
    const int k = blockIdx.x * 4 + (t >> 6);
    const int lane = t & 63;
    const int j = lane >> 2, dpart = lane & 3;
    const int u = (j >> 2) & 3, v = j & 3;
    int woff[3];
    #pragma unroll
    for (int m = 0; m < 3; ++m) woff[m] = m * 8192 + (3 - u) * 4 + (3 - v);
    float a0 = 0.f, a1 = 0.f, a2 = 0.f;
    for (int i = 0; i < 128; ++i) {
        int d = dpart * 128 + i;
        float cw = cbF[(size_t)d * 512 + k];
        a0 = fmaf(cw, cWd[woff[0] + d * 16], a0);
        a1 = fmaf(cw, cWd[woff[1] + d * 16], a1);
        a2 = fmaf(cw, cWd[woff[2] + d * 16], a2);
    }
    a0 += __shfl_xor(a0, 1); a0 += __shfl_xor(a0, 2);
    a1 += __shfl_xor(a1, 1); a1 += __shfl_xor(a1, 2);
    a2 += __shfl_xor(a2, 1); a2 += __shfl_xor(a2, 2);
    if (dpart == 0) {
        U[k * 48 +  0 + j] = a0 + cbd[0];
        U[k * 48 + 16 + j] = a1 + cbd[1];
        U[k * 48 + 32 + j] = a2 + cbd[2];
    }
}

// ---------------------------------------------------------------------------
// k_main helpers (zq = pair base: zH = zq, zL = zq + 2560 shorts; rows 40 shorts)
// ---------------------------------------------------------------------------
static __device__ __forceinline__ void conv_step(
        const float* __restrict__ patch, const float* __restrict__ cWe,
        const float* __restrict__ cbe, int dc, int t,
        unsigned short* __restrict__ zq) {
    const int cd = t & 31;
    const int ps = (t >> 5) * 8;
    const float4* wv = (const float4*)(cWe + (size_t)(dc + cd) * 48);
    const float bias = cbe[dc + cd];
    float za[8];
    #pragma unroll
    for (int p = 0; p < 8; ++p) za[p] = bias;
    #pragma unroll
    for (int q4 = 0; q4 < 12; ++q4) {
        float4 wq = wv[q4];
        #pragma unroll
        for (int p = 0; p < 8; ++p) {
            float4 v = ((const float4*)(patch + (ps + p) * 48))[q4];
            za[p] = fmaf(v.x, wq.x, za[p]);
            za[p] = fmaf(v.y, wq.y, za[p]);
            za[p] = fmaf(v.z, wq.z, za[p]);
            za[p] = fmaf(v.w, wq.w, za[p]);
        }
    }
    #pragma unroll
    for (int p = 0; p < 8; ++p) {
        float z = fmaxf(za[p], 0.f);
        unsigned short h = f2bf(z);
        zq[(ps + p) * 40 + cd] = h;
        zq[2560 + (ps + p) * 40 + cd] = f2bf(z - bfu(h));
    }
}

static __device__ __forceinline__ void mfma_step(
        const unsigned short* __restrict__ zq,
        const unsigned short* __restrict__ cbHT,
        const unsigned short* __restrict__ cbLT,
        int dcPrev, int wave, int quad, int lcol, int flag, floatx4 (&acc)[4][8]) {
    short8 aH[4], aL[4];
    #pragma unroll
    for (int mt = 0; mt < 4; ++mt) {
        aH[mt] = *(const short8*)(zq + (mt * 16 + lcol) * 40 + quad * 8);
        aL[mt] = *(const short8*)(zq + 2560 + (mt * 16 + lcol) * 40 + quad * 8);
    }
    #pragma unroll
    for (int j = 0; j < 8; ++j) {
        int code = (wave * 8 + j) * 16 + lcol;
        short8 bH = *(const short8*)(cbHT + (size_t)code * 512 + dcPrev + quad * 8);
        #pragma unroll
        for (int mt = 0; mt < 4; ++mt) {
            acc[mt][j] = __builtin_amdgcn_mfma_f32_16x16x32_bf16(aH[mt], bH, acc[mt][j], 0, 0, 0);
            acc[mt][j] = __builtin_amdgcn_mfma_f32_16x16x32_bf16(aL[mt], bH, acc[mt][j], 0, 0, 0);
        }
    }
    if (!flag) {   // fp32 inputs: third term zh*cbL
        #pragma unroll
        for (int j = 0; j < 8; ++j) {
            int code = (wave * 8 + j) * 16 + lcol;
            short8 bL = *(const short8*)(cbLT + (size_t)code * 512 + dcPrev + quad * 8);
            #pragma unroll
            for (int mt = 0; mt < 4; ++mt)
                acc[mt][j] = __builtin_amdgcn_mfma_f32_16x16x32_bf16(aH[mt], bL, acc[mt][j], 0, 0, 0);
        }
    }
}

static __device__ __forceinline__ void outz_step(
        const unsigned short* __restrict__ zq, int dcPrev, int t,
        int b, int SP0, float* __restrict__ out_z) {
    const int col = t & 63, g = t >> 6;
    const unsigned short* ph = zq + col * 40 + 8 * g;
    const unsigned short* pl = zq + 2560 + col * 40 + 8 * g;
    ushort4 h0 = *(const ushort4*)(ph);
    ushort4 h1 = *(const ushort4*)(ph + 4);
    ushort4 l0 = *(const ushort4*)(pl);
    ushort4 l1 = *(const ushort4*)(pl + 4);
    size_t base = (size_t)(b * 512 + dcPrev + 8 * g) * 1024 + SP0 + col;
    out_z[base         ] = bfu(h0.x) + bfu(l0.x);
    out_z[base + 1024  ] = bfu(h0.y) + bfu(l0.y);
    out_z[base + 2048  ] = bfu(h0.z) + bfu(l0.z);
    out_z[base + 3072  ] = bfu(h0.w) + bfu(l0.w);
    out_z[base + 4096  ] = bfu(h1.x) + bfu(l1.x);
    out_z[base + 5120  ] = bfu(h1.y) + bfu(l1.y);
    out_z[base + 6144  ] = bfu(h1.z) + bfu(l1.z);
    out_z[base + 7168  ] = bfu(h1.w) + bfu(l1.w);
}

// best/second combine: (a1,ak,a2) <- merge (o1,ok,o2)
static __device__ __forceinline__ void bmerge(float& a1, int& ak, float& a2,
                                              float o1, int ok, float o2) {
    if (o1 < a1)      { a2 = fminf(a1, o2); a1 = o1; ak = ok; }
    else if (o1 > a1) { a2 = fminf(a2, o1); }
    else              { a2 = a1; if (ok < ak) ak = ok; }   // exact tie -> gap 0 (suspect)
}

// ---------------------------------------------------------------------------
// FUSED main v3 (single-barrier pipelined): per 64-pos block, d-chunks of 32.
//   iter dc: sync; conv(dc)->buf p; mfma(dc-32)<-buf 1-p (B direct from L2);
//            outz(dc-32)<-buf 1-p.
// Epilogue: shuffle-reduced best/second argmin -> idx + suspects; fused emb.
// LDS: patch 12288 | z pairs 2x10240 = 32768 B total.
// ---------------------------------------------------------------------------
__global__ __launch_bounds__(256, 2) void k_main(
        const void* __restrict__ x, const float* __restrict__ cWe,
        const float* __restrict__ cbe, const int* __restrict__ flagp,
        const unsigned short* __restrict__ cbHT, const unsigned short* __restrict__ cbLT,
        const float* __restrict__ cbT, const float* __restrict__ w2,
        float* __restrict__ out_z, float* __restrict__ out_e,
        int* __restrict__ idx, int* __restrict__ scnt, int* __restrict__ spos,
        int skipTail) {
    __shared__ __align__(16) char smc[32768];
    float* patch = (float*)smc;                               // [64][48] fp32
    unsigned short* zb = (unsigned short*)(smc + 12288);      // 2 pairs x 5120 shorts

    const int t = threadIdx.x;
    const int P0 = blockIdx.x * 64;
    const int b = P0 >> 10, SP0 = P0 & 1023;
    const int flag = *flagp;
    const int wave = t >> 6, lane = t & 63;
    const int quad = lane >> 4, lcol = lane & 15;

    // stage x patches once
    for (int e = t; e < 3072; e += 256) {
        int pid = e / 48, kk = e % 48;
        int c = kk >> 4, r = (kk >> 2) & 3, s = kk & 3;
        int pos = P0 + pid;
        int bb = pos >> 10, sp = pos & 1023, i = sp >> 5, j = sp & 31;
        patch[pid * 48 + kk] = ldin(x, ((bb * 3 + c) * 128 + (i * 4 + r)) * 128 + (j * 4 + s), flag);
    }

    floatx4 acc[4][8];
    #pragma unroll
    for (int mt = 0; mt < 4; ++mt)
        #pragma unroll
        for (int j = 0; j < 8; ++j) acc[mt][j] = (floatx4){0.f, 0.f, 0.f, 0.f};

    __syncthreads();
    conv_step(patch, cWe, cbe, 0, t, zb);            // chunk 0 -> pair 0
    for (int dc = 32; dc < 512; dc += 32) {
        __syncthreads();
        const int p = (dc >> 5) & 1;
        conv_step(patch, cWe, cbe, dc, t, zb + p * 5120);
        mfma_step(zb + (p ^ 1) * 5120, cbHT, cbLT, dc - 32, wave, quad, lcol, flag, acc);
        outz_step(zb + (p ^ 1) * 5120, dc - 32, t, b, SP0, out_z);
    }
    __syncthreads();
    mfma_step(zb + 5120, cbHT, cbLT, 480, wave, quad, lcol, flag, acc);
    outz_step(zb + 5120, 480, t, b, SP0, out_z);

    // ---- epilogue: per-lane best/second over its 8 codes, then shuffle ----
    float s1[4][4], s2[4][4]; int k1[4][4];
    #pragma unroll
    for (int mt = 0; mt < 4; ++mt)
        #pragma unroll
        for (int r = 0; r < 4; ++r) { s1[mt][r] = 1e30f; s2[mt][r] = 1e30f; k1[mt][r] = 511; }
    #pragma unroll
    for (int j = 0; j < 8; ++j) {
        int code = (wave * 8 + j) * 16 + lcol;
        float wk = w2[code];
        #pragma unroll
        for (int mt = 0; mt < 4; ++mt)
            #pragma unroll
            for (int r = 0; r < 4; ++r) {
                float s = wk - 2.f * acc[mt][j][r];
                bmerge(s1[mt][r], k1[mt][r], s2[mt][r], s, code, 1e30f);
            }
    }
    // overlay reduction arrays on patch region (patch dead after last conv+sync)
    float* sS1 = (float*)smc;             // [64 pos][4 wave]
    int*   sK1 = (int*)(smc + 1024);
    float* sS2 = (float*)(smc + 2048);
    int*   ii  = (int*)(smc + 3072);      // [64]
    #pragma unroll
    for (int mt = 0; mt < 4; ++mt)
        #pragma unroll
        for (int r = 0; r < 4; ++r) {
            float a1 = s1[mt][r], a2 = s2[mt][r]; int ak = k1[mt][r];
            #pragma unroll
            for (int m = 1; m < 16; m <<= 1) {
                float o1 = __shfl_xor(a1, m);
                float o2 = __shfl_xor(a2, m);
                int   ok = __shfl_xor(ak, m);
                bmerge(a1, ak, a2, o1, ok, o2);
            }
            if (lcol == 0) {
                int pos = mt * 16 + quad * 4 + r;
                sS1[pos * 4 + wave] = a1;
                sK1[pos * 4 + wave] = ak;
                sS2[pos * 4 + wave] = a2;
            }
        }
    __syncthreads();
    if (t < 64) {
        float a1 = sS1[t * 4]; int ak = sK1[t * 4]; float a2 = sS2[t * 4];
        #pragma unroll
        for (int w = 1; w < 4; ++w)
            bmerge(a1, ak, a2, sS1[t * 4 + w], sK1[t * 4 + w], sS2[t * 4 + w]);
        ak &= 511;
        ii[t] = ak;
        idx[P0 + t] = ak;
        if (a2 - a1 < EPS_GAP) {
            int slot = atomicAdd(scnt, 1);
            if (slot < MAXSUS) spos[slot] = P0 + t;
        }
    }
    __syncthreads();

    // ---- fused emb: out_e[b][d][SP0+sp] = cbT[ii[sp]][d] ----
    const int sp = t & 63, dq = t >> 6;
    const float* row = cbT + (size_t)ii[sp] * 512;
    const size_t obase = ((size_t)b * 512) * 1024 + SP0 + sp;
    for (int d0 = dq * 128; d0 < dq * 128 + 128; d0 += 4) {
        if (skipTail && b == 31 && d0 >= 448) break;
        float4 v = *(const float4*)(row + d0);
        out_e[obase + (size_t)(d0    ) * 1024] = v.x;
        out_e[obase + (size_t)(d0 + 1) * 1024] = v.y;
        out_e[obase + (size_t)(d0 + 2) * 1024] = v.z;
        out_e[obase + (size_t)(d0 + 3) * 1024] = v.w;
    }
}

// ---------------------------------------------------------------------------
// Exact fp64 rescore of suspect positions; patches idx and emb column.
// ---------------------------------------------------------------------------
__global__ __launch_bounds__(256) void k_rescore(
        const float* __restrict__ out_z, const float* __restrict__ cbT,
        const double* __restrict__ w2d, int* __restrict__ idx,
        const int* __restrict__ scnt, const int* __restrict__ spos,
        float* __restrict__ out_e, int skipTail) {
    __shared__ float zsh[512];
    __shared__ float rs[256];
    __shared__ int rk[256];
    __shared__ int bc[2];
    const int t = threadIdx.x;
    int n = *scnt; if (n > MAXSUS) n = MAXSUS;
    for (int s = blockIdx.x; s < n; s += gridDim.x) {
        int p = spos[s] & 32767;
        int b = p >> 10, sp = p & 1023;
        __syncthreads();
        zsh[t]       = out_z[(size_t)(b * 512 + t) * 1024 + sp];
        zsh[t + 256] = out_z[(size_t)(b * 512 + t + 256) * 1024 + sp];
        __syncthreads();
        float bs = 1e30f; int bk = 511;
        for (int cc = 0; cc < 2; ++cc) {
            int k = t + cc * 256;
            double a = 0.0;
            const float* row = cbT + (size_t)k * 512;
            for (int d = 0; d < 512; ++d) a = fma((double)zsh[d], (double)row[d], a);
            float sc = (float)(w2d[k] - 2.0 * a);
            if (sc < bs || (sc == bs && k < bk)) { bs = sc; bk = k; }
        }
        rs[t] = bs; rk[t] = bk;
        __syncthreads();
        for (int str = 128; str > 0; str >>= 1) {
            if (t < str) {
                float so = rs[t + str]; int ko = rk[t + str];
                if (so < rs[t] || (so == rs[t] && ko < rk[t])) { rs[t] = so; rk[t] = ko; }
            }
            __syncthreads();
        }
        if (t == 0) {
            int kstar = rk[0] & 511;
            int old = idx[p] & 511;
            bc[0] = kstar; bc[1] = (kstar != old);
            idx[p] = kstar;
        }
        __syncthreads();
        if (bc[1]) {
            int kk = bc[0];
            for (int d = t; d < 512; d += 256) {
                if (skipTail && b == 31 && d >= 448) continue;
                out_e[(size_t)(b * 512 + d) * 1024 + sp] = cbT[(size_t)kk * 512 + d];
            }
        }
    }
}

// ---------------------------------------------------------------------------
__global__ __launch_bounds__(256) void k_recon(
        const float* __restrict__ U, const int* __restrict__ idx,
        float* __restrict__ out_r) {
    const int pos = blockIdx.x * 256 + threadIdx.x;
    const int id = idx[pos] & 511;
    const int b = pos >> 10, sp = pos & 1023, i = sp >> 5, j = sp & 31;
    const float* u = &U[(size_t)id * 48];
    #pragma unroll
    for (int c = 0; c < 3; ++c)
        #pragma unroll
        for (int uu = 0; uu < 4; ++uu) {
            float4 q = *(const float4*)(&u[c * 16 + uu * 4]);
            float4 o;
            o.x = 1.f / (1.f + __expf(-q.x));
            o.y = 1.f / (1.f + __expf(-q.y));
            o.z = 1.f / (1.f + __expf(-q.z));
            o.w = 1.f / (1.f + __expf(-q.w));
            *(float4*)(&out_r[((size_t)((b * 3 + c) * 128) + (i * 4 + uu)) * 128 + j * 4]) = o;
        }
}

// ---------------------------------------------------------------------------
__global__ __launch_bounds__(1024) void k_fixup(
        const void* __restrict__ cb, const int* __restrict__ flagp,
        const int* __restrict__ idx, float* __restrict__ out_e) {
    __shared__ int ii[1024];
    __shared__ int sflag;
    const int t = threadIdx.x;
    if (t == 0) sflag = *flagp;
    ii[t] = idx[31744 + t] & 511;
    __syncthreads();
    const int flag = sflag;
    for (int e = t; e < 65536; e += 1024) {
        int d = 448 + (e >> 10), sp = e & 1023;
        out_e[((size_t)(31 * 512 + d)) * 1024 + sp] = ldin(cb, (size_t)d * 512 + ii[sp], flag);
    }
}

// ---------------------------------------------------------------------------
extern "C" void kernel_launch(void* const* d_in, const int* in_sizes, int n_in,
                              void* d_out, int out_size, void* d_ws, size_t ws_size,
                              hipStream_t stream) {
    const void* x  = d_in[0];
    const void* We = d_in[1];
    const void* be = d_in[2];
    const void* Wd = d_in[3];
    const void* bd = d_in[4];
    const void* cb = d_in[5];

    float* out   = (float*)d_out;
    float* out_r = out;                       // 1,572,864 fp32 (6.29 MB)
    float* out_z = out + 1572864;             // 16,777,216 fp32
    float* out_e = out + 18350080;            // 16,777,216 fp32

    // Read-mostly tables in out_r (recon overwrites at the very end):
    char* Rb = (char*)out_r;
    float* cbF          = (float*)(Rb);                    // 1,048,576 B
    float* cbT          = (float*)(Rb + 1048576);          // 1,048,576 B
    float* cWe          = (float*)(Rb + 2097152);          //    98,304 B
    float* cbe          = (float*)(Rb + 2195456);          //     2,048 B
    float* cWd          = (float*)(Rb + 2197504);          //    98,304 B
    float* cbd          = (float*)(Rb + 2295808);          //        64 B
    unsigned short* cbHT= (unsigned short*)(Rb + 2295872); //   524,288 B
    unsigned short* cbLT= (unsigned short*)(Rb + 2820160); //   524,288 B

    // Tail scratch: prefer d_ws; else last 256 KB of out_e (fixup required).
    int tailWS = (ws_size >= 262144) ? 1 : 0;
    char* Tbase = tailWS ? (char*)d_ws : ((char*)out_e + 66846720);
    int skipTail = tailWS ? 0 : 1;
    int*    idx  = (int*)   (Tbase);            // 131,072 B
    float*  U    = (float*) (Tbase + 131072);   //  98,304 B
    float*  w2   = (float*) (Tbase + 229376);   //   2,048 B
    double* w2d  = (double*)(Tbase + 231424);   //   4,096 B
    int*    flag = (int*)   (Tbase + 235520);   //      64 B
    int*    scnt = (int*)   (Tbase + 235584);   //      64 B
    int*    spos = (int*)   (Tbase + 235648);   //  16,384 B

    k_sniff<<<1, 64, 0, stream>>>(cb, flag, scnt);
    k_canonW<<<195, 256, 0, stream>>>(We, be, Wd, bd, flag, cWe, cbe, cWd, cbd);
    k_prepcb<<<dim3(8, 8), 256, 0, stream>>>(cb, flag, cbF, cbT, cbHT, cbLT);
    k_w2<<<8, 64, 0, stream>>>(cbF, w2, w2d);
    k_udec<<<128, 256, 0, stream>>>(cbF, cWd, cbd, U);

    k_main<<<512, 256, 0, stream>>>(x, cWe, cbe, flag, cbHT, cbLT, cbT, w2,
                                    out_z, out_e, idx, scnt, spos, skipTail);

    k_rescore<<<128, 256, 0, stream>>>(out_z, cbT, w2d, idx, scnt, spos, out_e, skipTail);
    k_recon<<<128, 256, 0, stream>>>(U, idx, out_r);
    if (skipTail)
        k_fixup<<<1, 1024, 0, stream>>>(cb, flag, idx, out_e);
}